// Round 1
// baseline (1339.129 us; speedup 1.0000x reference)
//
#include <hip/hip_runtime.h>

using u16 = unsigned short;
typedef __attribute__((ext_vector_type(4))) float f32x4;
typedef __attribute__((ext_vector_type(8))) short bf16x8;
typedef unsigned short u16x8 __attribute__((ext_vector_type(8)));

static constexpr int S_TOK = 8192;   // B*T
static constexpr int NE    = 8;      // experts
static constexpr int CAP   = 1024;   // capacity = S/E
static constexpr int DDIM  = 2048;   // model dim
static constexpr int FDIM  = 8192;   // ffn dim

__device__ __forceinline__ u16 f2bf(float f) {
  union { float fv; unsigned uv; } v; v.fv = f;
  unsigned r = v.uv + 0x7fffu + ((v.uv >> 16) & 1u);
  return (u16)(r >> 16);
}

__device__ __forceinline__ float gelu_tanh(float x) {
  // jax.nn.gelu approximate=True
  float u = 0.7978845608028654f * (x + 0.044715f * x * x * x);
  float t = 1.0f - 2.0f / (__expf(2.0f * u) + 1.0f);
  return 0.5f * x * (1.0f + t);
}

__device__ __forceinline__ void gl_lds16(const void* g, void* l) {
  __builtin_amdgcn_global_load_lds(
      (const __attribute__((address_space(1))) unsigned int*)g,
      (__attribute__((address_space(3))) unsigned int*)l, 16, 0, 0);
}

// ---------------- gating: logits fp32, softmax, argmax ----------------
__global__ __launch_bounds__(256) void gating_kernel(
    const float* __restrict__ x, const float* __restrict__ wg,
    int* __restrict__ tok_expert, float* __restrict__ tok_gate) {
  int s = blockIdx.x * 4 + (threadIdx.x >> 6);
  int lane = threadIdx.x & 63;
  const float4* xv = (const float4*)(x + (size_t)s * DDIM + lane * 32);
  float acc[8];
#pragma unroll
  for (int e = 0; e < 8; ++e) acc[e] = 0.f;
#pragma unroll
  for (int j = 0; j < 8; ++j) {
    float4 xx = xv[j];
#pragma unroll
    for (int c = 0; c < 4; ++c) {
      int i = lane * 32 + j * 4 + c;
      const float4* wrow = (const float4*)(wg + (size_t)i * 8);
      float4 w0 = wrow[0], w1 = wrow[1];
      float xe = (c == 0) ? xx.x : (c == 1) ? xx.y : (c == 2) ? xx.z : xx.w;
      acc[0] += xe * w0.x; acc[1] += xe * w0.y; acc[2] += xe * w0.z; acc[3] += xe * w0.w;
      acc[4] += xe * w1.x; acc[5] += xe * w1.y; acc[6] += xe * w1.z; acc[7] += xe * w1.w;
    }
  }
#pragma unroll
  for (int off = 32; off > 0; off >>= 1)
#pragma unroll
    for (int e = 0; e < 8; ++e) acc[e] += __shfl_xor(acc[e], off, 64);
  if (lane == 0) {
    float m = acc[0]; int ai = 0;
#pragma unroll
    for (int e = 1; e < 8; ++e) if (acc[e] > m) { m = acc[e]; ai = e; }
    float sum = 0.f;
#pragma unroll
    for (int e = 0; e < 8; ++e) sum += expf(acc[e] - m);
    tok_expert[s] = ai;
    tok_gate[s] = 1.0f / sum;   // softmax prob of argmax expert
  }
}

__global__ void init_slots(int* tok_of_slot, float* gate_of_slot) {
  int i = blockIdx.x * 256 + threadIdx.x;
  tok_of_slot[i] = -1;
  gate_of_slot[i] = 0.f;
}

// -------- deterministic capacity assignment (cumsum over token order) --------
__global__ __launch_bounds__(1024) void scan_kernel(
    const int* __restrict__ tok_expert, const float* __restrict__ tok_gate,
    int* __restrict__ tok_of_slot, float* __restrict__ gate_of_slot) {
  __shared__ int cnt[1024][8];
  int t = threadIdx.x;
  int e8[8];
  int local[8];
#pragma unroll
  for (int e = 0; e < 8; ++e) local[e] = 0;
#pragma unroll
  for (int j = 0; j < 8; ++j) {
    int e = tok_expert[t * 8 + j];
    e8[j] = e;
    local[e]++;
  }
#pragma unroll
  for (int e = 0; e < 8; ++e) cnt[t][e] = local[e];
  __syncthreads();
  for (int off = 1; off < 1024; off <<= 1) {
    int v[8];
    bool has = (t >= off);
    if (has) {
#pragma unroll
      for (int e = 0; e < 8; ++e) v[e] = cnt[t - off][e];
    }
    __syncthreads();
    if (has) {
#pragma unroll
      for (int e = 0; e < 8; ++e) cnt[t][e] += v[e];
    }
    __syncthreads();
  }
  int base[8];
#pragma unroll
  for (int e = 0; e < 8; ++e) base[e] = (t == 0) ? 0 : cnt[t - 1][e];
#pragma unroll
  for (int j = 0; j < 8; ++j) {
    int s = t * 8 + j;
    int e = e8[j];
    int p = base[e]++;
    if (p < CAP) {
      tok_of_slot[e * CAP + p] = s;
      gate_of_slot[e * CAP + p] = tok_gate[s];
    }
  }
}

// ---------------- dispatch: gather x rows -> bf16 Xd [E][CAP][D] ----------------
__global__ __launch_bounds__(256) void scatter_kernel(
    const int* __restrict__ tok_of_slot, const float* __restrict__ x,
    u16* __restrict__ Xd) {
  int slot = blockIdx.x;
  int s = tok_of_slot[slot];
  if (s < 0) return;
  int t = threadIdx.x;
  const float4* xr = (const float4*)(x + (size_t)s * DDIM + t * 8);
  float4 a = xr[0], b = xr[1];
  u16x8 v;
  v[0] = f2bf(a.x); v[1] = f2bf(a.y); v[2] = f2bf(a.z); v[3] = f2bf(a.w);
  v[4] = f2bf(b.x); v[5] = f2bf(b.y); v[6] = f2bf(b.z); v[7] = f2bf(b.w);
  *(u16x8*)(Xd + (size_t)slot * DDIM + t * 8) = v;
}

// ---------------- fp32 [E][R][Cn] -> bf16 transposed [E][Cn][R] ----------------
template <int R, int Cn>
__global__ __launch_bounds__(256) void convt_kernel(
    const float* __restrict__ w, u16* __restrict__ wt) {
  __shared__ float tile[64][65];
  int e = blockIdx.z, rt = blockIdx.y, ct = blockIdx.x, t = threadIdx.x;
  const float* wp = w + ((size_t)e * R + (size_t)rt * 64) * Cn + (size_t)ct * 64;
#pragma unroll
  for (int p = 0; p < 4; ++p) {
    int i = t + p * 256;
    int r = i >> 4, c4 = (i & 15) * 4;
    float4 v = *(const float4*)(wp + (size_t)r * Cn + c4);
    tile[r][c4 + 0] = v.x; tile[r][c4 + 1] = v.y;
    tile[r][c4 + 2] = v.z; tile[r][c4 + 3] = v.w;
  }
  __syncthreads();
  u16* op = wt + ((size_t)e * Cn + (size_t)ct * 64) * R + (size_t)rt * 64;
#pragma unroll
  for (int p = 0; p < 2; ++p) {
    int i = t + p * 256;
    int c = i >> 3, r8 = (i & 7) * 8;
    u16x8 o;
#pragma unroll
    for (int j = 0; j < 8; ++j) o[j] = f2bf(tile[r8 + j][c]);
    *(u16x8*)(op + (size_t)c * R + r8) = o;
  }
}

// ---------------- m97-structure bf16 GEMM: C[1024xN] = A[1024xK] * Bt[NxK]^T ----------------
// EPI=0: out = gelu -> bf16 H[e][1024][NDIM]
// EPI=1: out = gate-scaled scatter to fp32 Fout[token][NDIM]
template <int KDIM, int NDIM, int EPI>
__global__ __launch_bounds__(256) void moe_gemm(
    const u16* __restrict__ A, const u16* __restrict__ Bt,
    u16* __restrict__ Hout, float* __restrict__ Fout,
    const int* __restrict__ tok_of_slot, const float* __restrict__ gate_of_slot,
    int e_base) {
  constexpr int MDIM = 1024;
  __shared__ u16 As[128 * 32];
  __shared__ u16 Bs[128 * 32];
  int t = threadIdx.x;
  int m0 = blockIdx.x * 128, n0 = blockIdx.y * 128;
  int e = e_base + blockIdx.z;
  const u16* Ae = A + (size_t)blockIdx.z * MDIM * KDIM;
  const u16* Be = Bt + (size_t)blockIdx.z * NDIM * KDIM;
  int lane = t & 63, wave = t >> 6;
  int wr = wave >> 1, wc = wave & 1;

  f32x4 zero = {0.f, 0.f, 0.f, 0.f};
  f32x4 acc[4][4];
#pragma unroll
  for (int m = 0; m < 4; ++m)
#pragma unroll
    for (int n = 0; n < 4; ++n) acc[m][n] = zero;

  int arow = t >> 2, akq = (t & 3) * 8;
  const u16* aptr = Ae + ((size_t)(m0 + arow)) * KDIM + akq;
  const u16* bptr = Be + ((size_t)(n0 + arow)) * KDIM + akq;
  u16* asl = As + t * 8;   // byte offset t*16, linear per-lane as gload_lds requires
  u16* bsl = Bs + t * 8;

  for (int kt = 0; kt < KDIM; kt += 32) {
    gl_lds16(aptr + kt, asl);
    gl_lds16(aptr + kt + (size_t)64 * KDIM, asl + 64 * 32);
    gl_lds16(bptr + kt, bsl);
    gl_lds16(bptr + kt + (size_t)64 * KDIM, bsl + 64 * 32);
    __syncthreads();

    bf16x8 af[4], bfv[4];
    int kro = (lane >> 4) * 8;
#pragma unroll
    for (int m = 0; m < 4; ++m)
      af[m] = *(const bf16x8*)(As + (wr * 64 + m * 16 + (lane & 15)) * 32 + kro);
#pragma unroll
    for (int n = 0; n < 4; ++n)
      bfv[n] = *(const bf16x8*)(Bs + (wc * 64 + n * 16 + (lane & 15)) * 32 + kro);
#pragma unroll
    for (int m = 0; m < 4; ++m)
#pragma unroll
      for (int n = 0; n < 4; ++n)
        acc[m][n] = __builtin_amdgcn_mfma_f32_16x16x32_bf16(af[m], bfv[n], acc[m][n], 0, 0, 0);
    __syncthreads();
  }

  if (EPI == 0) {
    u16* Hrow = Hout + (size_t)blockIdx.z * MDIM * NDIM;
#pragma unroll
    for (int m = 0; m < 4; ++m) {
#pragma unroll
      for (int r = 0; r < 4; ++r) {
        int row = m0 + wr * 64 + m * 16 + (lane >> 4) * 4 + r;
#pragma unroll
        for (int n = 0; n < 4; ++n) {
          int col = n0 + wc * 64 + n * 16 + (lane & 15);
          Hrow[(size_t)row * NDIM + col] = f2bf(gelu_tanh(acc[m][n][r]));
        }
      }
    }
  } else {
#pragma unroll
    for (int m = 0; m < 4; ++m) {
#pragma unroll
      for (int r = 0; r < 4; ++r) {
        int slot_in_e = m0 + wr * 64 + m * 16 + (lane >> 4) * 4 + r;
        int gslot = e * CAP + slot_in_e;
        int s = tok_of_slot[gslot];
        if (s >= 0) {
          float g = gate_of_slot[gslot];
#pragma unroll
          for (int n = 0; n < 4; ++n) {
            int col = n0 + wc * 64 + n * 16 + (lane & 15);
            Fout[(size_t)s * NDIM + col] = g * acc[m][n][r];
          }
        }
      }
    }
  }
}

extern "C" void kernel_launch(void* const* d_in, const int* in_sizes, int n_in,
                              void* d_out, int out_size, void* d_ws, size_t ws_size,
                              hipStream_t stream) {
  (void)in_sizes; (void)n_in;
  const float* x  = (const float*)d_in[0];
  const float* wg = (const float*)d_in[1];
  const float* w1 = (const float*)d_in[2];
  const float* w2 = (const float*)d_in[3];
  float* out = (float*)d_out;

  char* ws = (char*)d_ws;
  size_t off = 0;
  auto alloc = [&](size_t b) {
    off = (off + 255) & ~(size_t)255;
    char* p = ws + off;
    off += b;
    return p;
  };
  int*   tok_expert   = (int*)alloc((size_t)S_TOK * 4);
  float* tok_gate     = (float*)alloc((size_t)S_TOK * 4);
  int*   tok_of_slot  = (int*)alloc((size_t)NE * CAP * 4);
  float* gate_of_slot = (float*)alloc((size_t)NE * CAP * 4);
  u16*   Xd           = (u16*)alloc((size_t)NE * CAP * DDIM * 2);
  size_t off_common = off;

  const size_t H_big  = (size_t)NE * CAP * FDIM * 2;   // 134 MB
  const size_t WT_big = (size_t)NE * DDIM * FDIM * 2;  // 268 MB
  const size_t H_sm   = (size_t)CAP * FDIM * 2;        // 16.8 MB
  const size_t WT_sm  = (size_t)DDIM * FDIM * 2;       // 33.5 MB
  bool big = ws_size >= off_common + H_big + WT_big + 1024;

  hipMemsetAsync(out, 0, (size_t)out_size * 4, stream);
  hipMemsetAsync(Xd, 0, (size_t)NE * CAP * DDIM * 2, stream);
  gating_kernel<<<S_TOK / 4, 256, 0, stream>>>(x, wg, tok_expert, tok_gate);
  init_slots<<<(NE * CAP) / 256, 256, 0, stream>>>(tok_of_slot, gate_of_slot);
  scan_kernel<<<1, 1024, 0, stream>>>(tok_expert, tok_gate, tok_of_slot, gate_of_slot);
  scatter_kernel<<<NE * CAP, 256, 0, stream>>>(tok_of_slot, x, Xd);

  if (big) {
    u16* H  = (u16*)alloc(H_big);
    u16* WT = (u16*)alloc(WT_big);
    convt_kernel<DDIM, FDIM><<<dim3(FDIM / 64, DDIM / 64, NE), 256, 0, stream>>>(w1, WT);
    moe_gemm<DDIM, FDIM, 0><<<dim3(8, FDIM / 128, NE), 256, 0, stream>>>(
        Xd, WT, H, nullptr, tok_of_slot, gate_of_slot, 0);
    convt_kernel<FDIM, DDIM><<<dim3(DDIM / 64, FDIM / 64, NE), 256, 0, stream>>>(w2, WT);
    moe_gemm<FDIM, DDIM, 1><<<dim3(8, DDIM / 128, NE), 256, 0, stream>>>(
        H, WT, nullptr, out, tok_of_slot, gate_of_slot, 0);
  } else {
    u16* H  = (u16*)alloc(H_sm);
    u16* WT = (u16*)alloc(WT_sm);
    for (int e = 0; e < NE; ++e) {
      convt_kernel<DDIM, FDIM><<<dim3(FDIM / 64, DDIM / 64, 1), 256, 0, stream>>>(
          w1 + (size_t)e * DDIM * FDIM, WT);
      moe_gemm<DDIM, FDIM, 0><<<dim3(8, FDIM / 128, 1), 256, 0, stream>>>(
          Xd + (size_t)e * CAP * DDIM, WT, H, nullptr, tok_of_slot, gate_of_slot, e);
      convt_kernel<FDIM, DDIM><<<dim3(DDIM / 64, FDIM / 64, 1), 256, 0, stream>>>(
          w2 + (size_t)e * FDIM * DDIM, WT);
      moe_gemm<FDIM, DDIM, 1><<<dim3(8, DDIM / 128, 1), 256, 0, stream>>>(
          H, WT, nullptr, out, tok_of_slot, gate_of_slot, e);
    }
  }
}

// Round 2
// 1220.008 us; speedup vs baseline: 1.0976x; 1.0976x over previous
//
#include <hip/hip_runtime.h>

using u16 = unsigned short;
typedef __attribute__((ext_vector_type(4))) float f32x4;
typedef __attribute__((ext_vector_type(8))) short bf16x8;
typedef unsigned short u16x8 __attribute__((ext_vector_type(8)));

static constexpr int S_TOK = 8192;   // B*T
static constexpr int NE    = 8;      // experts
static constexpr int CAP   = 1024;   // capacity = S/E
static constexpr int DDIM  = 2048;   // model dim
static constexpr int FDIM  = 8192;   // ffn dim

__device__ __forceinline__ u16 f2bf(float f) {
  union { float fv; unsigned uv; } v; v.fv = f;
  unsigned r = v.uv + 0x7fffu + ((v.uv >> 16) & 1u);
  return (u16)(r >> 16);
}

__device__ __forceinline__ float gelu_tanh(float x) {
  // jax.nn.gelu approximate=True
  float u = 0.7978845608028654f * (x + 0.044715f * x * x * x);
  float t = 1.0f - 2.0f / (__expf(2.0f * u) + 1.0f);
  return 0.5f * x * (1.0f + t);
}

__device__ __forceinline__ void gl_lds16(const void* g, void* l) {
  __builtin_amdgcn_global_load_lds(
      (const __attribute__((address_space(1))) unsigned int*)g,
      (__attribute__((address_space(3))) unsigned int*)l, 16, 0, 0);
}

// ---------------- gating: logits fp32, softmax, argmax ----------------
__global__ __launch_bounds__(256) void gating_kernel(
    const float* __restrict__ x, const float* __restrict__ wg,
    int* __restrict__ tok_expert, float* __restrict__ tok_gate) {
  int s = blockIdx.x * 4 + (threadIdx.x >> 6);
  int lane = threadIdx.x & 63;
  const float4* xv = (const float4*)(x + (size_t)s * DDIM + lane * 32);
  float acc[8];
#pragma unroll
  for (int e = 0; e < 8; ++e) acc[e] = 0.f;
#pragma unroll
  for (int j = 0; j < 8; ++j) {
    float4 xx = xv[j];
#pragma unroll
    for (int c = 0; c < 4; ++c) {
      int i = lane * 32 + j * 4 + c;
      const float4* wrow = (const float4*)(wg + (size_t)i * 8);
      float4 w0 = wrow[0], w1 = wrow[1];
      float xe = (c == 0) ? xx.x : (c == 1) ? xx.y : (c == 2) ? xx.z : xx.w;
      acc[0] += xe * w0.x; acc[1] += xe * w0.y; acc[2] += xe * w0.z; acc[3] += xe * w0.w;
      acc[4] += xe * w1.x; acc[5] += xe * w1.y; acc[6] += xe * w1.z; acc[7] += xe * w1.w;
    }
  }
#pragma unroll
  for (int off = 32; off > 0; off >>= 1)
#pragma unroll
    for (int e = 0; e < 8; ++e) acc[e] += __shfl_xor(acc[e], off, 64);
  if (lane == 0) {
    float m = acc[0]; int ai = 0;
#pragma unroll
    for (int e = 1; e < 8; ++e) if (acc[e] > m) { m = acc[e]; ai = e; }
    float sum = 0.f;
#pragma unroll
    for (int e = 0; e < 8; ++e) sum += expf(acc[e] - m);
    tok_expert[s] = ai;
    tok_gate[s] = 1.0f / sum;   // softmax prob of argmax expert
  }
}

__global__ void init_slots(int* tok_of_slot, float* gate_of_slot) {
  int i = blockIdx.x * 256 + threadIdx.x;
  tok_of_slot[i] = -1;
  gate_of_slot[i] = 0.f;
}

// -------- deterministic capacity assignment (cumsum over token order) --------
__global__ __launch_bounds__(1024) void scan_kernel(
    const int* __restrict__ tok_expert, const float* __restrict__ tok_gate,
    int* __restrict__ tok_of_slot, float* __restrict__ gate_of_slot) {
  __shared__ int cnt[1024][8];
  int t = threadIdx.x;
  int e8[8];
  int local[8];
#pragma unroll
  for (int e = 0; e < 8; ++e) local[e] = 0;
#pragma unroll
  for (int j = 0; j < 8; ++j) {
    int e = tok_expert[t * 8 + j];
    e8[j] = e;
    local[e]++;
  }
#pragma unroll
  for (int e = 0; e < 8; ++e) cnt[t][e] = local[e];
  __syncthreads();
  for (int off = 1; off < 1024; off <<= 1) {
    int v[8];
    bool has = (t >= off);
    if (has) {
#pragma unroll
      for (int e = 0; e < 8; ++e) v[e] = cnt[t - off][e];
    }
    __syncthreads();
    if (has) {
#pragma unroll
      for (int e = 0; e < 8; ++e) cnt[t][e] += v[e];
    }
    __syncthreads();
  }
  int base[8];
#pragma unroll
  for (int e = 0; e < 8; ++e) base[e] = (t == 0) ? 0 : cnt[t - 1][e];
#pragma unroll
  for (int j = 0; j < 8; ++j) {
    int s = t * 8 + j;
    int e = e8[j];
    int p = base[e]++;
    if (p < CAP) {
      tok_of_slot[e * CAP + p] = s;
      gate_of_slot[e * CAP + p] = tok_gate[s];
    }
  }
}

// ---------------- dispatch: gather x rows -> bf16 Xd [E][CAP][D] ----------------
__global__ __launch_bounds__(256) void scatter_kernel(
    const int* __restrict__ tok_of_slot, const float* __restrict__ x,
    u16* __restrict__ Xd) {
  int slot = blockIdx.x;
  int s = tok_of_slot[slot];
  if (s < 0) return;
  int t = threadIdx.x;
  const float4* xr = (const float4*)(x + (size_t)s * DDIM + t * 8);
  float4 a = xr[0], b = xr[1];
  u16x8 v;
  v[0] = f2bf(a.x); v[1] = f2bf(a.y); v[2] = f2bf(a.z); v[3] = f2bf(a.w);
  v[4] = f2bf(b.x); v[5] = f2bf(b.y); v[6] = f2bf(b.z); v[7] = f2bf(b.w);
  *(u16x8*)(Xd + (size_t)slot * DDIM + t * 8) = v;
}

// ---------------- fp32 [E][R][Cn] -> bf16 transposed [E][Cn][R] ----------------
template <int R, int Cn>
__global__ __launch_bounds__(256) void convt_kernel(
    const float* __restrict__ w, u16* __restrict__ wt) {
  __shared__ float tile[64][65];
  int e = blockIdx.z, rt = blockIdx.y, ct = blockIdx.x, t = threadIdx.x;
  const float* wp = w + ((size_t)e * R + (size_t)rt * 64) * Cn + (size_t)ct * 64;
#pragma unroll
  for (int p = 0; p < 4; ++p) {
    int i = t + p * 256;
    int r = i >> 4, c4 = (i & 15) * 4;
    float4 v = *(const float4*)(wp + (size_t)r * Cn + c4);
    tile[r][c4 + 0] = v.x; tile[r][c4 + 1] = v.y;
    tile[r][c4 + 2] = v.z; tile[r][c4 + 3] = v.w;
  }
  __syncthreads();
  u16* op = wt + ((size_t)e * Cn + (size_t)ct * 64) * R + (size_t)rt * 64;
#pragma unroll
  for (int p = 0; p < 2; ++p) {
    int i = t + p * 256;
    int c = i >> 3, r8 = (i & 7) * 8;
    u16x8 o;
#pragma unroll
    for (int j = 0; j < 8; ++j) o[j] = f2bf(tile[r8 + j][c]);
    *(u16x8*)(op + (size_t)c * R + r8) = o;
  }
}

// ---------------- m97-structure bf16 GEMM: C[1024xN] = A[1024xK] * Bt[NxK]^T ----------------
// 1-D swizzled grid: id = ((nt * MT) + mt) * NEXP + ez
//   ez -> XCD (round-robin dispatch heuristic): each expert's working set stays
//   in one XCD's L2; the MT m-tiles sharing a B-panel are id-adjacent -> co-resident.
// EPI=0: out = gelu -> bf16 H[e][1024][NDIM]
// EPI=1: out = gate-scaled scatter to fp32 Fout[token][NDIM]
template <int KDIM, int NDIM, int EPI, int NEXP>
__global__ __launch_bounds__(256) void moe_gemm(
    const u16* __restrict__ A, const u16* __restrict__ Bt,
    u16* __restrict__ Hout, float* __restrict__ Fout,
    const int* __restrict__ tok_of_slot, const float* __restrict__ gate_of_slot,
    int e_base) {
  constexpr int MDIM = 1024;
  constexpr int MT = MDIM / 128;
  __shared__ u16 As[128 * 32];
  __shared__ u16 Bs[128 * 32];
  int t = threadIdx.x;

  int id = blockIdx.x;
  int ez = id & (NEXP - 1);
  int w  = id / NEXP;
  int mt = w & (MT - 1);
  int nt = w / MT;
  int m0 = mt * 128, n0 = nt * 128;
  int e = e_base + ez;

  const u16* Ae = A + (size_t)ez * MDIM * KDIM;
  const u16* Be = Bt + (size_t)ez * NDIM * KDIM;
  int lane = t & 63, wave = t >> 6;
  int wr = wave >> 1, wc = wave & 1;

  f32x4 zero = {0.f, 0.f, 0.f, 0.f};
  f32x4 acc[4][4];
#pragma unroll
  for (int m = 0; m < 4; ++m)
#pragma unroll
    for (int n = 0; n < 4; ++n) acc[m][n] = zero;

  int arow = t >> 2, akq = (t & 3) * 8;
  const u16* aptr = Ae + ((size_t)(m0 + arow)) * KDIM + akq;
  const u16* bptr = Be + ((size_t)(n0 + arow)) * KDIM + akq;
  u16* asl = As + t * 8;   // byte offset t*16, linear per-lane as gload_lds requires
  u16* bsl = Bs + t * 8;

  for (int kt = 0; kt < KDIM; kt += 32) {
    gl_lds16(aptr + kt, asl);
    gl_lds16(aptr + kt + (size_t)64 * KDIM, asl + 64 * 32);
    gl_lds16(bptr + kt, bsl);
    gl_lds16(bptr + kt + (size_t)64 * KDIM, bsl + 64 * 32);
    __syncthreads();

    bf16x8 af[4], bfv[4];
    int kro = (lane >> 4) * 8;
#pragma unroll
    for (int m = 0; m < 4; ++m)
      af[m] = *(const bf16x8*)(As + (wr * 64 + m * 16 + (lane & 15)) * 32 + kro);
#pragma unroll
    for (int n = 0; n < 4; ++n)
      bfv[n] = *(const bf16x8*)(Bs + (wc * 64 + n * 16 + (lane & 15)) * 32 + kro);
#pragma unroll
    for (int m = 0; m < 4; ++m)
#pragma unroll
      for (int n = 0; n < 4; ++n)
        acc[m][n] = __builtin_amdgcn_mfma_f32_16x16x32_bf16(af[m], bfv[n], acc[m][n], 0, 0, 0);
    __syncthreads();
  }

  if (EPI == 0) {
    u16* Hrow = Hout + (size_t)ez * MDIM * NDIM;
#pragma unroll
    for (int m = 0; m < 4; ++m) {
#pragma unroll
      for (int r = 0; r < 4; ++r) {
        int row = m0 + wr * 64 + m * 16 + (lane >> 4) * 4 + r;
#pragma unroll
        for (int n = 0; n < 4; ++n) {
          int col = n0 + wc * 64 + n * 16 + (lane & 15);
          Hrow[(size_t)row * NDIM + col] = f2bf(gelu_tanh(acc[m][n][r]));
        }
      }
    }
  } else {
#pragma unroll
    for (int m = 0; m < 4; ++m) {
#pragma unroll
      for (int r = 0; r < 4; ++r) {
        int slot_in_e = m0 + wr * 64 + m * 16 + (lane >> 4) * 4 + r;
        int gslot = e * CAP + slot_in_e;
        int s = tok_of_slot[gslot];
        if (s >= 0) {
          float g = gate_of_slot[gslot];
#pragma unroll
          for (int n = 0; n < 4; ++n) {
            int col = n0 + wc * 64 + n * 16 + (lane & 15);
            Fout[(size_t)s * NDIM + col] = g * acc[m][n][r];
          }
        }
      }
    }
  }
}

extern "C" void kernel_launch(void* const* d_in, const int* in_sizes, int n_in,
                              void* d_out, int out_size, void* d_ws, size_t ws_size,
                              hipStream_t stream) {
  (void)in_sizes; (void)n_in;
  const float* x  = (const float*)d_in[0];
  const float* wg = (const float*)d_in[1];
  const float* w1 = (const float*)d_in[2];
  const float* w2 = (const float*)d_in[3];
  float* out = (float*)d_out;

  char* ws = (char*)d_ws;
  size_t off = 0;
  auto alloc = [&](size_t b) {
    off = (off + 255) & ~(size_t)255;
    char* p = ws + off;
    off += b;
    return p;
  };
  int*   tok_expert   = (int*)alloc((size_t)S_TOK * 4);
  float* tok_gate     = (float*)alloc((size_t)S_TOK * 4);
  int*   tok_of_slot  = (int*)alloc((size_t)NE * CAP * 4);
  float* gate_of_slot = (float*)alloc((size_t)NE * CAP * 4);
  u16*   Xd           = (u16*)alloc((size_t)NE * CAP * DDIM * 2);
  size_t off_common = off;

  const size_t H_big  = (size_t)NE * CAP * FDIM * 2;   // 134 MB
  const size_t WT_big = (size_t)NE * DDIM * FDIM * 2;  // 268 MB
  const size_t H_sm   = (size_t)CAP * FDIM * 2;        // 16.8 MB
  const size_t WT_sm  = (size_t)DDIM * FDIM * 2;       // 33.5 MB
  bool big = ws_size >= off_common + H_big + WT_big + 1024;

  hipMemsetAsync(out, 0, (size_t)out_size * 4, stream);
  hipMemsetAsync(Xd, 0, (size_t)NE * CAP * DDIM * 2, stream);
  gating_kernel<<<S_TOK / 4, 256, 0, stream>>>(x, wg, tok_expert, tok_gate);
  init_slots<<<(NE * CAP) / 256, 256, 0, stream>>>(tok_of_slot, gate_of_slot);
  scan_kernel<<<1, 1024, 0, stream>>>(tok_expert, tok_gate, tok_of_slot, gate_of_slot);
  scatter_kernel<<<NE * CAP, 256, 0, stream>>>(tok_of_slot, x, Xd);

  if (big) {
    u16* H  = (u16*)alloc(H_big);
    u16* WT = (u16*)alloc(WT_big);
    convt_kernel<DDIM, FDIM><<<dim3(FDIM / 64, DDIM / 64, NE), 256, 0, stream>>>(w1, WT);
    moe_gemm<DDIM, FDIM, 0, NE><<<dim3(NE * 8 * (FDIM / 128)), 256, 0, stream>>>(
        Xd, WT, H, nullptr, tok_of_slot, gate_of_slot, 0);
    convt_kernel<FDIM, DDIM><<<dim3(DDIM / 64, FDIM / 64, NE), 256, 0, stream>>>(w2, WT);
    moe_gemm<FDIM, DDIM, 1, NE><<<dim3(NE * 8 * (DDIM / 128)), 256, 0, stream>>>(
        H, WT, nullptr, out, tok_of_slot, gate_of_slot, 0);
  } else {
    u16* H  = (u16*)alloc(H_sm);
    u16* WT = (u16*)alloc(WT_sm);
    for (int e = 0; e < NE; ++e) {
      convt_kernel<DDIM, FDIM><<<dim3(FDIM / 64, DDIM / 64, 1), 256, 0, stream>>>(
          w1 + (size_t)e * DDIM * FDIM, WT);
      moe_gemm<DDIM, FDIM, 0, 1><<<dim3(8 * (FDIM / 128)), 256, 0, stream>>>(
          Xd + (size_t)e * CAP * DDIM, WT, H, nullptr, tok_of_slot, gate_of_slot, e);
      convt_kernel<FDIM, DDIM><<<dim3(DDIM / 64, FDIM / 64, 1), 256, 0, stream>>>(
          w2 + (size_t)e * FDIM * DDIM, WT);
      moe_gemm<FDIM, DDIM, 1, 1><<<dim3(8 * (DDIM / 128)), 256, 0, stream>>>(
          H, WT, nullptr, out, tok_of_slot, gate_of_slot, e);
    }
  }
}

// Round 3
// 994.451 us; speedup vs baseline: 1.3466x; 1.2268x over previous
//
#include <hip/hip_runtime.h>

using u16 = unsigned short;
typedef __attribute__((ext_vector_type(4))) float f32x4;
typedef __attribute__((ext_vector_type(8))) short bf16x8;
typedef unsigned short u16x8 __attribute__((ext_vector_type(8)));

static constexpr int S_TOK = 8192;   // B*T
static constexpr int NE    = 8;      // experts
static constexpr int CAP   = 1024;   // capacity = S/E
static constexpr int DDIM  = 2048;   // model dim
static constexpr int FDIM  = 8192;   // ffn dim

#define S_VMCNT(n) asm volatile("s_waitcnt vmcnt(" #n ")" ::: "memory")
#define S_BAR()                                  \
  do {                                           \
    __builtin_amdgcn_sched_barrier(0);           \
    __builtin_amdgcn_s_barrier();                \
    __builtin_amdgcn_sched_barrier(0);           \
  } while (0)

__device__ __forceinline__ u16 f2bf(float f) {
  union { float fv; unsigned uv; } v; v.fv = f;
  unsigned r = v.uv + 0x7fffu + ((v.uv >> 16) & 1u);
  return (u16)(r >> 16);
}

__device__ __forceinline__ float gelu_tanh(float x) {
  float u = 0.7978845608028654f * (x + 0.044715f * x * x * x);
  float t = 1.0f - 2.0f / (__expf(2.0f * u) + 1.0f);
  return 0.5f * x * (1.0f + t);
}

__device__ __forceinline__ void gl_lds16(const void* g, void* l) {
  __builtin_amdgcn_global_load_lds(
      (const __attribute__((address_space(1))) unsigned int*)g,
      (__attribute__((address_space(3))) unsigned int*)l, 16, 0, 0);
}

// ---------------- gating: logits fp32, softmax, argmax ----------------
__global__ __launch_bounds__(256) void gating_kernel(
    const float* __restrict__ x, const float* __restrict__ wg,
    int* __restrict__ tok_expert, float* __restrict__ tok_gate) {
  int s = blockIdx.x * 4 + (threadIdx.x >> 6);
  int lane = threadIdx.x & 63;
  const float4* xv = (const float4*)(x + (size_t)s * DDIM + lane * 32);
  float acc[8];
#pragma unroll
  for (int e = 0; e < 8; ++e) acc[e] = 0.f;
#pragma unroll
  for (int j = 0; j < 8; ++j) {
    float4 xx = xv[j];
#pragma unroll
    for (int c = 0; c < 4; ++c) {
      int i = lane * 32 + j * 4 + c;
      const float4* wrow = (const float4*)(wg + (size_t)i * 8);
      float4 w0 = wrow[0], w1 = wrow[1];
      float xe = (c == 0) ? xx.x : (c == 1) ? xx.y : (c == 2) ? xx.z : xx.w;
      acc[0] += xe * w0.x; acc[1] += xe * w0.y; acc[2] += xe * w0.z; acc[3] += xe * w0.w;
      acc[4] += xe * w1.x; acc[5] += xe * w1.y; acc[6] += xe * w1.z; acc[7] += xe * w1.w;
    }
  }
#pragma unroll
  for (int off = 32; off > 0; off >>= 1)
#pragma unroll
    for (int e = 0; e < 8; ++e) acc[e] += __shfl_xor(acc[e], off, 64);
  if (lane == 0) {
    float m = acc[0]; int ai = 0;
#pragma unroll
    for (int e = 1; e < 8; ++e) if (acc[e] > m) { m = acc[e]; ai = e; }
    float sum = 0.f;
#pragma unroll
    for (int e = 0; e < 8; ++e) sum += expf(acc[e] - m);
    tok_expert[s] = ai;
    tok_gate[s] = 1.0f / sum;
  }
}

__global__ void init_slots(int* tok_of_slot, float* gate_of_slot) {
  int i = blockIdx.x * 256 + threadIdx.x;
  tok_of_slot[i] = -1;
  gate_of_slot[i] = 0.f;
}

// -------- deterministic capacity assignment (cumsum over token order) --------
__global__ __launch_bounds__(1024) void scan_kernel(
    const int* __restrict__ tok_expert, const float* __restrict__ tok_gate,
    int* __restrict__ tok_of_slot, float* __restrict__ gate_of_slot) {
  __shared__ int cnt[1024][8];
  int t = threadIdx.x;
  int e8[8];
  int local[8];
#pragma unroll
  for (int e = 0; e < 8; ++e) local[e] = 0;
#pragma unroll
  for (int j = 0; j < 8; ++j) {
    int e = tok_expert[t * 8 + j];
    e8[j] = e;
    local[e]++;
  }
#pragma unroll
  for (int e = 0; e < 8; ++e) cnt[t][e] = local[e];
  __syncthreads();
  for (int off = 1; off < 1024; off <<= 1) {
    int v[8];
    bool has = (t >= off);
    if (has) {
#pragma unroll
      for (int e = 0; e < 8; ++e) v[e] = cnt[t - off][e];
    }
    __syncthreads();
    if (has) {
#pragma unroll
      for (int e = 0; e < 8; ++e) cnt[t][e] += v[e];
    }
    __syncthreads();
  }
  int base[8];
#pragma unroll
  for (int e = 0; e < 8; ++e) base[e] = (t == 0) ? 0 : cnt[t - 1][e];
#pragma unroll
  for (int j = 0; j < 8; ++j) {
    int s = t * 8 + j;
    int e = e8[j];
    int p = base[e]++;
    if (p < CAP) {
      tok_of_slot[e * CAP + p] = s;
      gate_of_slot[e * CAP + p] = tok_gate[s];
    }
  }
}

// ---------------- dispatch: gather x rows -> bf16 Xd [E][CAP][D] ----------------
__global__ __launch_bounds__(256) void scatter_kernel(
    const int* __restrict__ tok_of_slot, const float* __restrict__ x,
    u16* __restrict__ Xd) {
  int slot = blockIdx.x;
  int s = tok_of_slot[slot];
  if (s < 0) return;
  int t = threadIdx.x;
  const float4* xr = (const float4*)(x + (size_t)s * DDIM + t * 8);
  float4 a = xr[0], b = xr[1];
  u16x8 v;
  v[0] = f2bf(a.x); v[1] = f2bf(a.y); v[2] = f2bf(a.z); v[3] = f2bf(a.w);
  v[4] = f2bf(b.x); v[5] = f2bf(b.y); v[6] = f2bf(b.z); v[7] = f2bf(b.w);
  *(u16x8*)(Xd + (size_t)slot * DDIM + t * 8) = v;
}

// ---------------- fp32 [E][R][Cn] -> bf16 transposed [E][Cn][R] ----------------
template <int R, int Cn>
__global__ __launch_bounds__(256) void convt_kernel(
    const float* __restrict__ w, u16* __restrict__ wt) {
  __shared__ float tile[64][65];
  int e = blockIdx.z, rt = blockIdx.y, ct = blockIdx.x, t = threadIdx.x;
  const float* wp = w + ((size_t)e * R + (size_t)rt * 64) * Cn + (size_t)ct * 64;
#pragma unroll
  for (int p = 0; p < 4; ++p) {
    int i = t + p * 256;
    int r = i >> 4, c4 = (i & 15) * 4;
    float4 v = *(const float4*)(wp + (size_t)r * Cn + c4);
    tile[r][c4 + 0] = v.x; tile[r][c4 + 1] = v.y;
    tile[r][c4 + 2] = v.z; tile[r][c4 + 3] = v.w;
  }
  __syncthreads();
  u16* op = wt + ((size_t)e * Cn + (size_t)ct * 64) * R + (size_t)rt * 64;
#pragma unroll
  for (int p = 0; p < 2; ++p) {
    int i = t + p * 256;
    int c = i >> 3, r8 = (i & 7) * 8;
    u16x8 o;
#pragma unroll
    for (int j = 0; j < 8; ++j) o[j] = f2bf(tile[r8 + j][c]);
    *(u16x8*)(op + (size_t)c * R + r8) = o;
  }
}

// ---- pipelined bf16 GEMM: C[1024xN] = A[1024xK] * Bt[NxK]^T ----
// BM=128 BN=256 BK=64, 512 thr / 8 waves (2M x 4N, 64x64 per wave).
// 3-slot LDS ring (144 KiB), staged 2 K-tiles ahead via global_load_lds w=16,
// counted s_waitcnt vmcnt(6) once per K-tile (drain only in tail),
// (row&7)<<4 XOR swizzle (write: pre-swizzled global src; read: same XOR).
// EPI=0: gelu -> bf16 H ; EPI=1: gate-scaled scatter to fp32 out.
template <int KDIM, int NDIM, int EPI, int NEXP>
__global__ __launch_bounds__(512) void moe_gemm(
    const u16* __restrict__ A, const u16* __restrict__ Bt,
    u16* __restrict__ Hout, float* __restrict__ Fout,
    const int* __restrict__ tok_of_slot, const float* __restrict__ gate_of_slot,
    int e_base) {
  constexpr int MDIM = 1024;
  constexpr int BM = 128, BN = 256;
  constexpr int MT = MDIM / BM;          // 8
  constexpr int NK = KDIM / 64;
  constexpr int ASZ = BM * 64;           // 8192 u16 (16 KB)
  constexpr int BSZ = BN * 64;           // 16384 u16 (32 KB)
  constexpr int SLOT = ASZ + BSZ;        // 24576 u16 (48 KB)
  __shared__ u16 lds[3 * SLOT];          // 144 KB

  const int t = threadIdx.x;
  const int lane = t & 63, wave = t >> 6;
  const int wr = wave >> 2, wc = wave & 3;   // 2 x 4

  int id = blockIdx.x;
  int ez = id & (NEXP - 1);
  int w = id / NEXP;
  int mt = w & (MT - 1);
  int nt = w / MT;
  int m0 = mt * BM, n0 = nt * BN;
  int e = e_base + ez;

  const u16* Ae = A + (size_t)ez * MDIM * KDIM;
  const u16* Be = Bt + (size_t)ez * (size_t)NDIM * KDIM;

  // ---- staging: thread t owns 16B at linear LDS offset l*8192 + t*16 per region.
  // row = l*64 + (t>>3); logical col_byte = ((t&7) ^ ((t>>3)&7)) << 4  (XOR involution)
  const int srow = t >> 3;
  const int scol = (((t & 7) ^ (srow & 7)) << 4) >> 1;  // u16 units
  const u16* aS0 = Ae + (size_t)(m0 + srow) * KDIM + scol;
  const u16* aS1 = aS0 + (size_t)64 * KDIM;
  const u16* bS0 = Be + (size_t)(n0 + srow) * KDIM + scol;
  const u16* bS1 = bS0 + (size_t)64 * KDIM;
  const u16* bS2 = bS0 + (size_t)128 * KDIM;
  const u16* bS3 = bS0 + (size_t)192 * KDIM;
  const int oA0 = t * 8;
  const int oA1 = 4096 + t * 8;
  const int oB0 = ASZ + t * 8;
  const int oB1 = ASZ + 4096 + t * 8;
  const int oB2 = ASZ + 8192 + t * 8;
  const int oB3 = ASZ + 12288 + t * 8;

  // ---- ds_read addressing (u16 offsets within a slot) ----
  const int aro = (wr * 64 + (lane & 15)) * 64;         // A row base
  const int bro = ASZ + (wc * 64 + (lane & 15)) * 64;   // B row base
  const int swz = (lane & 7) << 4;                      // byte key
  const int c0 = (((lane >> 4) * 16) ^ swz) >> 1;       // kk=0
  const int c1 = ((64 + (lane >> 4) * 16) ^ swz) >> 1;  // kk=1

  f32x4 acc[4][4];
#pragma unroll
  for (int m = 0; m < 4; ++m)
#pragma unroll
    for (int n = 0; n < 4; ++n) acc[m][n] = f32x4{0.f, 0.f, 0.f, 0.f};

  // ---- prologue: stage K-tiles 0,1 into slots 0,1 ----
#pragma unroll
  for (int p = 0; p < 2; ++p) {
    u16* nb = &lds[p * SLOT];
    size_t koff = (size_t)p * 64;
    gl_lds16(aS0 + koff, nb + oA0);
    gl_lds16(aS1 + koff, nb + oA1);
    gl_lds16(bS0 + koff, nb + oB0);
    gl_lds16(bS1 + koff, nb + oB1);
    gl_lds16(bS2 + koff, nb + oB2);
    gl_lds16(bS3 + koff, nb + oB3);
  }
  S_VMCNT(6);
  S_BAR();

  int sidx = 0;
  for (int kt = 0; kt < NK; ++kt) {
    const u16* sb = &lds[sidx * SLOT];
    const bool do_stage = (kt + 2 < NK);
    int nslot = sidx + 2; if (nslot >= 3) nslot -= 3;
    u16* nb = &lds[nslot * SLOT];
    const size_t koff = (size_t)(kt + 2) * 64;

    // ---------- phase 1 (kk = 0) ----------
    bf16x8 af0[4], bf0[4];
#pragma unroll
    for (int m = 0; m < 4; ++m)
      af0[m] = *(const bf16x8*)(sb + aro + m * 1024 + c0);
#pragma unroll
    for (int n = 0; n < 4; ++n)
      bf0[n] = *(const bf16x8*)(sb + bro + n * 1024 + c0);
    if (do_stage) {
      gl_lds16(aS0 + koff, nb + oA0);
      gl_lds16(aS1 + koff, nb + oA1);
      gl_lds16(bS0 + koff, nb + oB0);
    }
    S_BAR();
    __builtin_amdgcn_s_setprio(1);
#pragma unroll
    for (int m = 0; m < 4; ++m)
#pragma unroll
      for (int n = 0; n < 4; ++n)
        acc[m][n] = __builtin_amdgcn_mfma_f32_16x16x32_bf16(af0[m], bf0[n], acc[m][n], 0, 0, 0);
    __builtin_amdgcn_s_setprio(0);
    S_BAR();

    // ---------- phase 2 (kk = 1) ----------
    bf16x8 af1[4], bf1[4];
#pragma unroll
    for (int m = 0; m < 4; ++m)
      af1[m] = *(const bf16x8*)(sb + aro + m * 1024 + c1);
#pragma unroll
    for (int n = 0; n < 4; ++n)
      bf1[n] = *(const bf16x8*)(sb + bro + n * 1024 + c1);
    if (do_stage) {
      gl_lds16(bS1 + koff, nb + oB1);
      gl_lds16(bS2 + koff, nb + oB2);
      gl_lds16(bS3 + koff, nb + oB3);
      S_VMCNT(6);     // tile kt+1 landed; tile kt+2 (6 loads) stays in flight
    } else {
      S_VMCNT(0);     // tail drain
    }
    S_BAR();
    __builtin_amdgcn_s_setprio(1);
#pragma unroll
    for (int m = 0; m < 4; ++m)
#pragma unroll
      for (int n = 0; n < 4; ++n)
        acc[m][n] = __builtin_amdgcn_mfma_f32_16x16x32_bf16(af1[m], bf1[n], acc[m][n], 0, 0, 0);
    __builtin_amdgcn_s_setprio(0);
    S_BAR();

    sidx = (sidx + 1 == 3) ? 0 : sidx + 1;
  }

  // ---------- epilogue ----------
  if (EPI == 0) {
    u16* Hrow = Hout + (size_t)ez * MDIM * NDIM;
#pragma unroll
    for (int m = 0; m < 4; ++m) {
#pragma unroll
      for (int r = 0; r < 4; ++r) {
        int row = m0 + wr * 64 + m * 16 + (lane >> 4) * 4 + r;
#pragma unroll
        for (int n = 0; n < 4; ++n) {
          int col = n0 + wc * 64 + n * 16 + (lane & 15);
          Hrow[(size_t)row * NDIM + col] = f2bf(gelu_tanh(acc[m][n][r]));
        }
      }
    }
  } else {
#pragma unroll
    for (int m = 0; m < 4; ++m) {
#pragma unroll
      for (int r = 0; r < 4; ++r) {
        int slot_in_e = m0 + wr * 64 + m * 16 + (lane >> 4) * 4 + r;
        int gslot = e * CAP + slot_in_e;
        int s = tok_of_slot[gslot];
        if (s >= 0) {
          float g = gate_of_slot[gslot];
#pragma unroll
          for (int n = 0; n < 4; ++n) {
            int col = n0 + wc * 64 + n * 16 + (lane & 15);
            Fout[(size_t)s * NDIM + col] = g * acc[m][n][r];
          }
        }
      }
    }
  }
}

extern "C" void kernel_launch(void* const* d_in, const int* in_sizes, int n_in,
                              void* d_out, int out_size, void* d_ws, size_t ws_size,
                              hipStream_t stream) {
  (void)in_sizes; (void)n_in;
  const float* x  = (const float*)d_in[0];
  const float* wg = (const float*)d_in[1];
  const float* w1 = (const float*)d_in[2];
  const float* w2 = (const float*)d_in[3];
  float* out = (float*)d_out;

  char* ws = (char*)d_ws;
  size_t off = 0;
  auto alloc = [&](size_t b) {
    off = (off + 255) & ~(size_t)255;
    char* p = ws + off;
    off += b;
    return p;
  };
  int*   tok_expert   = (int*)alloc((size_t)S_TOK * 4);
  float* tok_gate     = (float*)alloc((size_t)S_TOK * 4);
  int*   tok_of_slot  = (int*)alloc((size_t)NE * CAP * 4);
  float* gate_of_slot = (float*)alloc((size_t)NE * CAP * 4);
  u16*   Xd           = (u16*)alloc((size_t)NE * CAP * DDIM * 2);
  size_t off_common = off;

  const size_t H_big  = (size_t)NE * CAP * FDIM * 2;   // 134 MB
  const size_t WT_big = (size_t)NE * DDIM * FDIM * 2;  // 268 MB
  const size_t H_sm   = (size_t)CAP * FDIM * 2;        // 16.8 MB
  const size_t WT_sm  = (size_t)DDIM * FDIM * 2;       // 33.5 MB
  bool big = ws_size >= off_common + H_big + WT_big + 1024;

  hipMemsetAsync(out, 0, (size_t)out_size * 4, stream);
  hipMemsetAsync(Xd, 0, (size_t)NE * CAP * DDIM * 2, stream);
  gating_kernel<<<S_TOK / 4, 256, 0, stream>>>(x, wg, tok_expert, tok_gate);
  init_slots<<<(NE * CAP) / 256, 256, 0, stream>>>(tok_of_slot, gate_of_slot);
  scan_kernel<<<1, 1024, 0, stream>>>(tok_expert, tok_gate, tok_of_slot, gate_of_slot);
  scatter_kernel<<<NE * CAP, 256, 0, stream>>>(tok_of_slot, x, Xd);

  if (big) {
    u16* H  = (u16*)alloc(H_big);
    u16* WT = (u16*)alloc(WT_big);
    convt_kernel<DDIM, FDIM><<<dim3(FDIM / 64, DDIM / 64, NE), 256, 0, stream>>>(w1, WT);
    moe_gemm<DDIM, FDIM, 0, NE><<<dim3(NE * 8 * (FDIM / 256)), 512, 0, stream>>>(
        Xd, WT, H, nullptr, tok_of_slot, gate_of_slot, 0);
    convt_kernel<FDIM, DDIM><<<dim3(DDIM / 64, FDIM / 64, NE), 256, 0, stream>>>(w2, WT);
    moe_gemm<FDIM, DDIM, 1, NE><<<dim3(NE * 8 * (DDIM / 256)), 512, 0, stream>>>(
        H, WT, nullptr, out, tok_of_slot, gate_of_slot, 0);
  } else {
    u16* H  = (u16*)alloc(H_sm);
    u16* WT = (u16*)alloc(WT_sm);
    for (int e = 0; e < NE; ++e) {
      convt_kernel<DDIM, FDIM><<<dim3(FDIM / 64, DDIM / 64, 1), 256, 0, stream>>>(
          w1 + (size_t)e * DDIM * FDIM, WT);
      moe_gemm<DDIM, FDIM, 0, 1><<<dim3(8 * (FDIM / 256)), 512, 0, stream>>>(
          Xd + (size_t)e * CAP * DDIM, WT, H, nullptr, tok_of_slot, gate_of_slot, e);
      convt_kernel<FDIM, DDIM><<<dim3(DDIM / 64, FDIM / 64, 1), 256, 0, stream>>>(
          w2 + (size_t)e * FDIM * DDIM, WT);
      moe_gemm<FDIM, DDIM, 1, 1><<<dim3(8 * (DDIM / 256)), 512, 0, stream>>>(
          H, WT, nullptr, out, tok_of_slot, gate_of_slot, e);
    }
  }
}

// Round 4
// 911.996 us; speedup vs baseline: 1.4683x; 1.0904x over previous
//
#include <hip/hip_runtime.h>

using u16 = unsigned short;
typedef __attribute__((ext_vector_type(4))) float f32x4;
typedef __attribute__((ext_vector_type(8))) short bf16x8;
typedef unsigned short u16x8 __attribute__((ext_vector_type(8)));

static constexpr int S_TOK = 8192;   // B*T
static constexpr int NE    = 8;      // experts
static constexpr int CAP   = 1024;   // capacity = S/E
static constexpr int DDIM  = 2048;   // model dim
static constexpr int FDIM  = 8192;   // ffn dim

#define S_VMCNT(n) asm volatile("s_waitcnt vmcnt(" #n ")" ::: "memory")
#define S_BAR()                                  \
  do {                                           \
    __builtin_amdgcn_sched_barrier(0);           \
    __builtin_amdgcn_s_barrier();                \
    __builtin_amdgcn_sched_barrier(0);           \
  } while (0)

__device__ __forceinline__ u16 f2bf(float f) {
  union { float fv; unsigned uv; } v; v.fv = f;
  unsigned r = v.uv + 0x7fffu + ((v.uv >> 16) & 1u);
  return (u16)(r >> 16);
}

__device__ __forceinline__ float gelu_tanh(float x) {
  float u = 0.7978845608028654f * (x + 0.044715f * x * x * x);
  float t = 1.0f - 2.0f / (__expf(2.0f * u) + 1.0f);
  return 0.5f * x * (1.0f + t);
}

__device__ __forceinline__ void gl_lds16(const void* g, void* l) {
  __builtin_amdgcn_global_load_lds(
      (const __attribute__((address_space(1))) unsigned int*)g,
      (__attribute__((address_space(3))) unsigned int*)l, 16, 0, 0);
}

// ---------------- gating: logits fp32, softmax, argmax ----------------
__global__ __launch_bounds__(256) void gating_kernel(
    const float* __restrict__ x, const float* __restrict__ wg,
    int* __restrict__ tok_expert, float* __restrict__ tok_gate) {
  int s = blockIdx.x * 4 + (threadIdx.x >> 6);
  int lane = threadIdx.x & 63;
  const float4* xv = (const float4*)(x + (size_t)s * DDIM + lane * 32);
  float acc[8];
#pragma unroll
  for (int e = 0; e < 8; ++e) acc[e] = 0.f;
#pragma unroll
  for (int j = 0; j < 8; ++j) {
    float4 xx = xv[j];
#pragma unroll
    for (int c = 0; c < 4; ++c) {
      int i = lane * 32 + j * 4 + c;
      const float4* wrow = (const float4*)(wg + (size_t)i * 8);
      float4 w0 = wrow[0], w1 = wrow[1];
      float xe = (c == 0) ? xx.x : (c == 1) ? xx.y : (c == 2) ? xx.z : xx.w;
      acc[0] += xe * w0.x; acc[1] += xe * w0.y; acc[2] += xe * w0.z; acc[3] += xe * w0.w;
      acc[4] += xe * w1.x; acc[5] += xe * w1.y; acc[6] += xe * w1.z; acc[7] += xe * w1.w;
    }
  }
#pragma unroll
  for (int off = 32; off > 0; off >>= 1)
#pragma unroll
    for (int e = 0; e < 8; ++e) acc[e] += __shfl_xor(acc[e], off, 64);
  if (lane == 0) {
    float m = acc[0]; int ai = 0;
#pragma unroll
    for (int e = 1; e < 8; ++e) if (acc[e] > m) { m = acc[e]; ai = e; }
    float sum = 0.f;
#pragma unroll
    for (int e = 0; e < 8; ++e) sum += expf(acc[e] - m);
    tok_expert[s] = ai;
    tok_gate[s] = 1.0f / sum;
  }
}

__global__ void init_slots(int* tok_of_slot, float* gate_of_slot) {
  int i = blockIdx.x * 256 + threadIdx.x;
  tok_of_slot[i] = -1;
  gate_of_slot[i] = 0.f;
}

// -------- deterministic capacity assignment (cumsum over token order) --------
__global__ __launch_bounds__(1024) void scan_kernel(
    const int* __restrict__ tok_expert, const float* __restrict__ tok_gate,
    int* __restrict__ tok_of_slot, float* __restrict__ gate_of_slot) {
  __shared__ int cnt[1024][8];
  int t = threadIdx.x;
  int e8[8];
  int local[8];
#pragma unroll
  for (int e = 0; e < 8; ++e) local[e] = 0;
#pragma unroll
  for (int j = 0; j < 8; ++j) {
    int e = tok_expert[t * 8 + j];
    e8[j] = e;
    local[e]++;
  }
#pragma unroll
  for (int e = 0; e < 8; ++e) cnt[t][e] = local[e];
  __syncthreads();
  for (int off = 1; off < 1024; off <<= 1) {
    int v[8];
    bool has = (t >= off);
    if (has) {
#pragma unroll
      for (int e = 0; e < 8; ++e) v[e] = cnt[t - off][e];
    }
    __syncthreads();
    if (has) {
#pragma unroll
      for (int e = 0; e < 8; ++e) cnt[t][e] += v[e];
    }
    __syncthreads();
  }
  int base[8];
#pragma unroll
  for (int e = 0; e < 8; ++e) base[e] = (t == 0) ? 0 : cnt[t - 1][e];
#pragma unroll
  for (int j = 0; j < 8; ++j) {
    int s = t * 8 + j;
    int e = e8[j];
    int p = base[e]++;
    if (p < CAP) {
      tok_of_slot[e * CAP + p] = s;
      gate_of_slot[e * CAP + p] = tok_gate[s];
    }
  }
}

// ---------------- dispatch: gather x rows -> bf16 Xd [E][CAP][D] ----------------
__global__ __launch_bounds__(256) void scatter_kernel(
    const int* __restrict__ tok_of_slot, const float* __restrict__ x,
    u16* __restrict__ Xd) {
  int slot = blockIdx.x;
  int s = tok_of_slot[slot];
  if (s < 0) return;
  int t = threadIdx.x;
  const float4* xr = (const float4*)(x + (size_t)s * DDIM + t * 8);
  float4 a = xr[0], b = xr[1];
  u16x8 v;
  v[0] = f2bf(a.x); v[1] = f2bf(a.y); v[2] = f2bf(a.z); v[3] = f2bf(a.w);
  v[4] = f2bf(b.x); v[5] = f2bf(b.y); v[6] = f2bf(b.z); v[7] = f2bf(b.w);
  *(u16x8*)(Xd + (size_t)slot * DDIM + t * 8) = v;
}

// ---------------- fp32 [E][R][Cn] -> bf16 transposed [E][Cn][R] ----------------
template <int R, int Cn>
__global__ __launch_bounds__(256) void convt_kernel(
    const float* __restrict__ w, u16* __restrict__ wt) {
  __shared__ float tile[64][65];
  int e = blockIdx.z, rt = blockIdx.y, ct = blockIdx.x, t = threadIdx.x;
  const float* wp = w + ((size_t)e * R + (size_t)rt * 64) * Cn + (size_t)ct * 64;
#pragma unroll
  for (int p = 0; p < 4; ++p) {
    int i = t + p * 256;
    int r = i >> 4, c4 = (i & 15) * 4;
    float4 v = *(const float4*)(wp + (size_t)r * Cn + c4);
    tile[r][c4 + 0] = v.x; tile[r][c4 + 1] = v.y;
    tile[r][c4 + 2] = v.z; tile[r][c4 + 3] = v.w;
  }
  __syncthreads();
  u16* op = wt + ((size_t)e * Cn + (size_t)ct * 64) * R + (size_t)rt * 64;
#pragma unroll
  for (int p = 0; p < 2; ++p) {
    int i = t + p * 256;
    int c = i >> 3, r8 = (i & 7) * 8;
    u16x8 o;
#pragma unroll
    for (int j = 0; j < 8; ++j) o[j] = f2bf(tile[r8 + j][c]);
    *(u16x8*)(op + (size_t)c * R + r8) = o;
  }
}

// ---- pipelined bf16 GEMM: C[1024xN] = A[1024xK] * Bt[NxK]^T ----
// BM=BN=256, BK=64, 512 thr / 8 waves (2M x 4N), wave-tile 128x64.
// Double-buffered LDS (128 KiB), XOR-swizzled rows. ONE vmcnt(0)+barrier per
// K-tile (outstanding loads are a full body old -> drain ~free); stage for
// tile kt+1 issued right after the barrier (WAR-safe), latency hides under
// the 64-MFMA body. Body scheduling left to compiler (fine-grained lgkmcnt).
// EPI=0: gelu -> bf16 H ; EPI=1: gate-scaled scatter to fp32 out.
template <int KDIM, int NDIM, int EPI, int NEXP>
__global__ __launch_bounds__(512, 2) void moe_gemm(
    const u16* __restrict__ A, const u16* __restrict__ Bt,
    u16* __restrict__ Hout, float* __restrict__ Fout,
    const int* __restrict__ tok_of_slot, const float* __restrict__ gate_of_slot,
    int e_base) {
  constexpr int MDIM = 1024;
  constexpr int BM = 256, BN = 256, BK = 64;
  constexpr int MT = MDIM / BM;              // 4
  constexpr int NK = KDIM / BK;
  constexpr int ASZ = BM * BK;               // 16384 u16 (32 KB)
  constexpr int BUFSZ = 2 * ASZ;             // A+B per buffer
  __shared__ u16 lds[2 * BUFSZ];             // 128 KB

  const int t = threadIdx.x;
  const int lane = t & 63, wave = t >> 6;
  const int wr = wave >> 2, wc = wave & 3;   // 2 x 4

  int id = blockIdx.x;
  int ez = id & (NEXP - 1);
  int w = id / NEXP;
  int mt = w & (MT - 1);
  int nt = w / MT;
  int m0 = mt * BM, n0 = nt * BN;
  int e = e_base + ez;

  const u16* Ae = A + (size_t)ez * MDIM * KDIM;
  const u16* Be = Bt + (size_t)ez * (size_t)NDIM * KDIM;

  // staging: region = 2048 16B-chunks; thread handles c = t + p*512, p=0..3.
  // chunk c -> LDS linear offset c*16B (wave-uniform + lane*16 ✓);
  // row = c>>3, phys chunk pc = c&7 holds logical chunk j = pc ^ (row&7).
  const u16* aSrc[4];
  const u16* bSrc[4];
  int ldsOff[4];
#pragma unroll
  for (int p = 0; p < 4; ++p) {
    int c = t + p * 512;
    int row = c >> 3;
    int j = (c & 7) ^ (row & 7);
    aSrc[p] = Ae + (size_t)(m0 + row) * KDIM + j * 8;
    bSrc[p] = Be + (size_t)(n0 + row) * KDIM + j * 8;
    ldsOff[p] = c * 8;
  }

  // ds_read addressing (u16 offsets within buffer)
  const int aBase = (wr * 128 + (lane & 15)) * 64;        // A row base
  const int bBase = ASZ + (wc * 64 + (lane & 15)) * 64;   // B row base
  const int swz = (lane & 7) << 4;                        // byte key
  const int cK0 = ((((lane >> 4) * 16)) ^ swz) >> 1;      // kk=0, u16
  const int cK1 = ((64 + (lane >> 4) * 16) ^ swz) >> 1;   // kk=1, u16

  f32x4 acc[8][4];
#pragma unroll
  for (int m = 0; m < 8; ++m)
#pragma unroll
    for (int n = 0; n < 4; ++n) acc[m][n] = f32x4{0.f, 0.f, 0.f, 0.f};

  // prologue: stage K-tile 0 into buffer 0
#pragma unroll
  for (int p = 0; p < 4; ++p) gl_lds16(aSrc[p], &lds[ldsOff[p]]);
#pragma unroll
  for (int p = 0; p < 4; ++p) gl_lds16(bSrc[p], &lds[ASZ + ldsOff[p]]);

  for (int kt = 0; kt < NK; ++kt) {
    S_VMCNT(0);   // only this tile's loads outstanding (issued a body ago)
    S_BAR();
    if (kt + 1 < NK) {
      u16* nb = &lds[((kt + 1) & 1) * BUFSZ];
      const int ko = (kt + 1) * BK;
#pragma unroll
      for (int p = 0; p < 4; ++p) gl_lds16(aSrc[p] + ko, nb + ldsOff[p]);
#pragma unroll
      for (int p = 0; p < 4; ++p) gl_lds16(bSrc[p] + ko, nb + ASZ + ldsOff[p]);
    }
    const u16* sb = &lds[(kt & 1) * BUFSZ];

#pragma unroll
    for (int kk = 0; kk < 2; ++kk) {
      const int ck = kk ? cK1 : cK0;
      bf16x8 af[8], bv[4];
#pragma unroll
      for (int m = 0; m < 8; ++m)
        af[m] = *(const bf16x8*)(sb + aBase + m * 1024 + ck);
#pragma unroll
      for (int n = 0; n < 4; ++n)
        bv[n] = *(const bf16x8*)(sb + bBase + n * 1024 + ck);
      __builtin_amdgcn_s_setprio(1);
#pragma unroll
      for (int m = 0; m < 8; ++m)
#pragma unroll
        for (int n = 0; n < 4; ++n)
          acc[m][n] = __builtin_amdgcn_mfma_f32_16x16x32_bf16(af[m], bv[n], acc[m][n], 0, 0, 0);
      __builtin_amdgcn_s_setprio(0);
    }
  }

  // ---------- epilogue ----------
  if (EPI == 0) {
    u16* Hrow = Hout + (size_t)ez * MDIM * NDIM;
#pragma unroll
    for (int m = 0; m < 8; ++m) {
#pragma unroll
      for (int r = 0; r < 4; ++r) {
        int row = m0 + wr * 128 + m * 16 + (lane >> 4) * 4 + r;
#pragma unroll
        for (int n = 0; n < 4; ++n) {
          int col = n0 + wc * 64 + n * 16 + (lane & 15);
          Hrow[(size_t)row * NDIM + col] = f2bf(gelu_tanh(acc[m][n][r]));
        }
      }
    }
  } else {
#pragma unroll
    for (int m = 0; m < 8; ++m) {
#pragma unroll
      for (int r = 0; r < 4; ++r) {
        int slot_in_e = m0 + wr * 128 + m * 16 + (lane >> 4) * 4 + r;
        int gslot = e * CAP + slot_in_e;
        int s = tok_of_slot[gslot];
        if (s >= 0) {
          float g = gate_of_slot[gslot];
#pragma unroll
          for (int n = 0; n < 4; ++n) {
            int col = n0 + wc * 64 + n * 16 + (lane & 15);
            Fout[(size_t)s * NDIM + col] = g * acc[m][n][r];
          }
        }
      }
    }
  }
}

extern "C" void kernel_launch(void* const* d_in, const int* in_sizes, int n_in,
                              void* d_out, int out_size, void* d_ws, size_t ws_size,
                              hipStream_t stream) {
  (void)in_sizes; (void)n_in;
  const float* x  = (const float*)d_in[0];
  const float* wg = (const float*)d_in[1];
  const float* w1 = (const float*)d_in[2];
  const float* w2 = (const float*)d_in[3];
  float* out = (float*)d_out;

  char* ws = (char*)d_ws;
  size_t off = 0;
  auto alloc = [&](size_t b) {
    off = (off + 255) & ~(size_t)255;
    char* p = ws + off;
    off += b;
    return p;
  };
  int*   tok_expert   = (int*)alloc((size_t)S_TOK * 4);
  float* tok_gate     = (float*)alloc((size_t)S_TOK * 4);
  int*   tok_of_slot  = (int*)alloc((size_t)NE * CAP * 4);
  float* gate_of_slot = (float*)alloc((size_t)NE * CAP * 4);
  u16*   Xd           = (u16*)alloc((size_t)NE * CAP * DDIM * 2);
  size_t off_common = off;

  const size_t H_big  = (size_t)NE * CAP * FDIM * 2;   // 134 MB
  const size_t WT_big = (size_t)NE * DDIM * FDIM * 2;  // 268 MB
  const size_t H_sm   = (size_t)CAP * FDIM * 2;        // 16.8 MB
  const size_t WT_sm  = (size_t)DDIM * FDIM * 2;       // 33.5 MB
  bool big = ws_size >= off_common + H_big + WT_big + 1024;

  hipMemsetAsync(out, 0, (size_t)out_size * 4, stream);
  hipMemsetAsync(Xd, 0, (size_t)NE * CAP * DDIM * 2, stream);
  gating_kernel<<<S_TOK / 4, 256, 0, stream>>>(x, wg, tok_expert, tok_gate);
  init_slots<<<(NE * CAP) / 256, 256, 0, stream>>>(tok_of_slot, gate_of_slot);
  scan_kernel<<<1, 1024, 0, stream>>>(tok_expert, tok_gate, tok_of_slot, gate_of_slot);
  scatter_kernel<<<NE * CAP, 256, 0, stream>>>(tok_of_slot, x, Xd);

  if (big) {
    u16* H  = (u16*)alloc(H_big);
    u16* WT = (u16*)alloc(WT_big);
    convt_kernel<DDIM, FDIM><<<dim3(FDIM / 64, DDIM / 64, NE), 256, 0, stream>>>(w1, WT);
    moe_gemm<DDIM, FDIM, 0, NE><<<dim3(NE * 4 * (FDIM / 256)), 512, 0, stream>>>(
        Xd, WT, H, nullptr, tok_of_slot, gate_of_slot, 0);
    convt_kernel<FDIM, DDIM><<<dim3(DDIM / 64, FDIM / 64, NE), 256, 0, stream>>>(w2, WT);
    moe_gemm<FDIM, DDIM, 1, NE><<<dim3(NE * 4 * (DDIM / 256)), 512, 0, stream>>>(
        H, WT, nullptr, out, tok_of_slot, gate_of_slot, 0);
  } else {
    u16* H  = (u16*)alloc(H_sm);
    u16* WT = (u16*)alloc(WT_sm);
    for (int e = 0; e < NE; ++e) {
      convt_kernel<DDIM, FDIM><<<dim3(FDIM / 64, DDIM / 64, 1), 256, 0, stream>>>(
          w1 + (size_t)e * DDIM * FDIM, WT);
      moe_gemm<DDIM, FDIM, 0, 1><<<dim3(4 * (FDIM / 256)), 512, 0, stream>>>(
          Xd + (size_t)e * CAP * DDIM, WT, H, nullptr, tok_of_slot, gate_of_slot, e);
      convt_kernel<FDIM, DDIM><<<dim3(DDIM / 64, FDIM / 64, 1), 256, 0, stream>>>(
          w2 + (size_t)e * FDIM * DDIM, WT);
      moe_gemm<FDIM, DDIM, 1, 1><<<dim3(4 * (DDIM / 256)), 512, 0, stream>>>(
          H, WT, nullptr, out, tok_of_slot, gate_of_slot, e);
    }
  }
}

// Round 5
// 905.136 us; speedup vs baseline: 1.4795x; 1.0076x over previous
//
#include <hip/hip_runtime.h>

using u16 = unsigned short;
typedef __attribute__((ext_vector_type(4))) float f32x4;
typedef __attribute__((ext_vector_type(8))) short bf16x8;
typedef unsigned short u16x8 __attribute__((ext_vector_type(8)));

static constexpr int S_TOK = 8192;   // B*T
static constexpr int NE    = 8;      // experts
static constexpr int CAP   = 1024;   // capacity = S/E
static constexpr int DDIM  = 2048;   // model dim
static constexpr int FDIM  = 8192;   // ffn dim

#define S_VMCNT(n) asm volatile("s_waitcnt vmcnt(" #n ")" ::: "memory")
#define S_BAR()                                  \
  do {                                           \
    __builtin_amdgcn_sched_barrier(0);           \
    __builtin_amdgcn_s_barrier();                \
    __builtin_amdgcn_sched_barrier(0);           \
  } while (0)

__device__ __forceinline__ u16 f2bf(float f) {
  union { float fv; unsigned uv; } v; v.fv = f;
  unsigned r = v.uv + 0x7fffu + ((v.uv >> 16) & 1u);
  return (u16)(r >> 16);
}

__device__ __forceinline__ float gelu_tanh(float x) {
  float u = 0.7978845608028654f * (x + 0.044715f * x * x * x);
  float t = 1.0f - 2.0f / (__expf(2.0f * u) + 1.0f);
  return 0.5f * x * (1.0f + t);
}

__device__ __forceinline__ void gl_lds16(const void* g, void* l) {
  __builtin_amdgcn_global_load_lds(
      (const __attribute__((address_space(1))) unsigned int*)g,
      (__attribute__((address_space(3))) unsigned int*)l, 16, 0, 0);
}

// ---------------- fast zero fill (replaces slow rocclr fillBuffer) ----------------
__global__ __launch_bounds__(256) void fill_zero_kernel(float4* __restrict__ p, int n4) {
  int i = blockIdx.x * 256 + threadIdx.x;
  int stride = gridDim.x * 256;
  float4 z = {0.f, 0.f, 0.f, 0.f};
  for (; i < n4; i += stride) p[i] = z;
}

// ---------------- gating: logits fp32, softmax, argmax ----------------
__global__ __launch_bounds__(256) void gating_kernel(
    const float* __restrict__ x, const float* __restrict__ wg,
    int* __restrict__ tok_expert, float* __restrict__ tok_gate) {
  int s = blockIdx.x * 4 + (threadIdx.x >> 6);
  int lane = threadIdx.x & 63;
  const float4* xv = (const float4*)(x + (size_t)s * DDIM + lane * 32);
  float acc[8];
#pragma unroll
  for (int e = 0; e < 8; ++e) acc[e] = 0.f;
#pragma unroll
  for (int j = 0; j < 8; ++j) {
    float4 xx = xv[j];
#pragma unroll
    for (int c = 0; c < 4; ++c) {
      int i = lane * 32 + j * 4 + c;
      const float4* wrow = (const float4*)(wg + (size_t)i * 8);
      float4 w0 = wrow[0], w1 = wrow[1];
      float xe = (c == 0) ? xx.x : (c == 1) ? xx.y : (c == 2) ? xx.z : xx.w;
      acc[0] += xe * w0.x; acc[1] += xe * w0.y; acc[2] += xe * w0.z; acc[3] += xe * w0.w;
      acc[4] += xe * w1.x; acc[5] += xe * w1.y; acc[6] += xe * w1.z; acc[7] += xe * w1.w;
    }
  }
#pragma unroll
  for (int off = 32; off > 0; off >>= 1)
#pragma unroll
    for (int e = 0; e < 8; ++e) acc[e] += __shfl_xor(acc[e], off, 64);
  if (lane == 0) {
    float m = acc[0]; int ai = 0;
#pragma unroll
    for (int e = 1; e < 8; ++e) if (acc[e] > m) { m = acc[e]; ai = e; }
    float sum = 0.f;
#pragma unroll
    for (int e = 0; e < 8; ++e) sum += expf(acc[e] - m);
    tok_expert[s] = ai;
    tok_gate[s] = 1.0f / sum;
  }
}

__global__ void init_slots(int* tok_of_slot, float* gate_of_slot) {
  int i = blockIdx.x * 256 + threadIdx.x;
  tok_of_slot[i] = -1;
  gate_of_slot[i] = 0.f;
}

// -------- deterministic capacity assignment (cumsum over token order) --------
__global__ __launch_bounds__(1024) void scan_kernel(
    const int* __restrict__ tok_expert, const float* __restrict__ tok_gate,
    int* __restrict__ tok_of_slot, float* __restrict__ gate_of_slot) {
  __shared__ int cnt[1024][8];
  int t = threadIdx.x;
  int e8[8];
  int local[8];
#pragma unroll
  for (int e = 0; e < 8; ++e) local[e] = 0;
#pragma unroll
  for (int j = 0; j < 8; ++j) {
    int e = tok_expert[t * 8 + j];
    e8[j] = e;
    local[e]++;
  }
#pragma unroll
  for (int e = 0; e < 8; ++e) cnt[t][e] = local[e];
  __syncthreads();
  for (int off = 1; off < 1024; off <<= 1) {
    int v[8];
    bool has = (t >= off);
    if (has) {
#pragma unroll
      for (int e = 0; e < 8; ++e) v[e] = cnt[t - off][e];
    }
    __syncthreads();
    if (has) {
#pragma unroll
      for (int e = 0; e < 8; ++e) cnt[t][e] += v[e];
    }
    __syncthreads();
  }
  int base[8];
#pragma unroll
  for (int e = 0; e < 8; ++e) base[e] = (t == 0) ? 0 : cnt[t - 1][e];
#pragma unroll
  for (int j = 0; j < 8; ++j) {
    int s = t * 8 + j;
    int e = e8[j];
    int p = base[e]++;
    if (p < CAP) {
      tok_of_slot[e * CAP + p] = s;
      gate_of_slot[e * CAP + p] = tok_gate[s];
    }
  }
}

// ---- dispatch: gather x rows -> bf16 Xd [E][CAP][D]; empty slots -> zeros ----
__global__ __launch_bounds__(256) void scatter_kernel(
    const int* __restrict__ tok_of_slot, const float* __restrict__ x,
    u16* __restrict__ Xd) {
  int slot = blockIdx.x;
  int s = tok_of_slot[slot];
  int t = threadIdx.x;
  u16x8 v;
  if (s >= 0) {
    const float4* xr = (const float4*)(x + (size_t)s * DDIM + t * 8);
    float4 a = xr[0], b = xr[1];
    v[0] = f2bf(a.x); v[1] = f2bf(a.y); v[2] = f2bf(a.z); v[3] = f2bf(a.w);
    v[4] = f2bf(b.x); v[5] = f2bf(b.y); v[6] = f2bf(b.z); v[7] = f2bf(b.w);
  } else {
#pragma unroll
    for (int j = 0; j < 8; ++j) v[j] = 0;
  }
  *(u16x8*)(Xd + (size_t)slot * DDIM + t * 8) = v;
}

// ---------------- fp32 [E][R][Cn] -> bf16 transposed [E][Cn][R] ----------------
template <int R, int Cn>
__global__ __launch_bounds__(256) void convt_kernel(
    const float* __restrict__ w, u16* __restrict__ wt) {
  __shared__ float tile[64][65];
  int e = blockIdx.z, rt = blockIdx.y, ct = blockIdx.x, t = threadIdx.x;
  const float* wp = w + ((size_t)e * R + (size_t)rt * 64) * Cn + (size_t)ct * 64;
#pragma unroll
  for (int p = 0; p < 4; ++p) {
    int i = t + p * 256;
    int r = i >> 4, c4 = (i & 15) * 4;
    float4 v = *(const float4*)(wp + (size_t)r * Cn + c4);
    tile[r][c4 + 0] = v.x; tile[r][c4 + 1] = v.y;
    tile[r][c4 + 2] = v.z; tile[r][c4 + 3] = v.w;
  }
  __syncthreads();
  u16* op = wt + ((size_t)e * Cn + (size_t)ct * 64) * R + (size_t)rt * 64;
#pragma unroll
  for (int p = 0; p < 2; ++p) {
    int i = t + p * 256;
    int c = i >> 3, r8 = (i & 7) * 8;
    u16x8 o;
#pragma unroll
    for (int j = 0; j < 8; ++j) o[j] = f2bf(tile[r8 + j][c]);
    *(u16x8*)(op + (size_t)c * R + r8) = o;
  }
}

// ---- pipelined bf16 GEMM: C[1024xN] = A[1024xK] * Bt[NxK]^T ----
// BM=BN=256, BK=64, 512 thr / 8 waves (2M x 4N), wave-tile 128x64.
// Double-buffered LDS (128 KiB), XOR-swizzled rows. ONE vmcnt(0)+barrier per
// K-tile; stage for kt+1 issued right after the barrier, latency hides under
// the 64-MFMA body. EPI=0: gelu -> bf16 H ; EPI=1: gated scatter to fp32 out.
template <int KDIM, int NDIM, int EPI, int NEXP>
__global__ __launch_bounds__(512, 2) void moe_gemm(
    const u16* __restrict__ A, const u16* __restrict__ Bt,
    u16* __restrict__ Hout, float* __restrict__ Fout,
    const int* __restrict__ tok_of_slot, const float* __restrict__ gate_of_slot,
    int e_base) {
  constexpr int MDIM = 1024;
  constexpr int BM = 256, BN = 256, BK = 64;
  constexpr int MT = MDIM / BM;              // 4
  constexpr int NK = KDIM / BK;
  constexpr int ASZ = BM * BK;               // 16384 u16 (32 KB)
  constexpr int BUFSZ = 2 * ASZ;             // A+B per buffer
  __shared__ u16 lds[2 * BUFSZ];             // 128 KB

  const int t = threadIdx.x;
  const int lane = t & 63, wave = t >> 6;
  const int wr = wave >> 2, wc = wave & 3;   // 2 x 4

  int id = blockIdx.x;
  int ez = id & (NEXP - 1);
  int w = id / NEXP;
  int mt = w & (MT - 1);
  int nt = w / MT;
  int m0 = mt * BM, n0 = nt * BN;
  int e = e_base + ez;

  const u16* Ae = A + (size_t)ez * MDIM * KDIM;
  const u16* Be = Bt + (size_t)ez * (size_t)NDIM * KDIM;

  const u16* aSrc[4];
  const u16* bSrc[4];
  int ldsOff[4];
#pragma unroll
  for (int p = 0; p < 4; ++p) {
    int c = t + p * 512;
    int row = c >> 3;
    int j = (c & 7) ^ (row & 7);
    aSrc[p] = Ae + (size_t)(m0 + row) * KDIM + j * 8;
    bSrc[p] = Be + (size_t)(n0 + row) * KDIM + j * 8;
    ldsOff[p] = c * 8;
  }

  const int aBase = (wr * 128 + (lane & 15)) * 64;        // A row base
  const int bBase = ASZ + (wc * 64 + (lane & 15)) * 64;   // B row base
  const int swz = (lane & 7) << 4;                        // byte key
  const int cK0 = ((((lane >> 4) * 16)) ^ swz) >> 1;      // kk=0, u16
  const int cK1 = ((64 + (lane >> 4) * 16) ^ swz) >> 1;   // kk=1, u16

  f32x4 acc[8][4];
#pragma unroll
  for (int m = 0; m < 8; ++m)
#pragma unroll
    for (int n = 0; n < 4; ++n) acc[m][n] = f32x4{0.f, 0.f, 0.f, 0.f};

  // prologue: stage K-tile 0 into buffer 0
#pragma unroll
  for (int p = 0; p < 4; ++p) gl_lds16(aSrc[p], &lds[ldsOff[p]]);
#pragma unroll
  for (int p = 0; p < 4; ++p) gl_lds16(bSrc[p], &lds[ASZ + ldsOff[p]]);

  for (int kt = 0; kt < NK; ++kt) {
    S_VMCNT(0);   // only this tile's loads outstanding (issued a body ago)
    S_BAR();
    if (kt + 1 < NK) {
      u16* nb = &lds[((kt + 1) & 1) * BUFSZ];
      const int ko = (kt + 1) * BK;
#pragma unroll
      for (int p = 0; p < 4; ++p) gl_lds16(aSrc[p] + ko, nb + ldsOff[p]);
#pragma unroll
      for (int p = 0; p < 4; ++p) gl_lds16(bSrc[p] + ko, nb + ASZ + ldsOff[p]);
    }
    const u16* sb = &lds[(kt & 1) * BUFSZ];

#pragma unroll
    for (int kk = 0; kk < 2; ++kk) {
      const int ck = kk ? cK1 : cK0;
      bf16x8 af[8], bv[4];
#pragma unroll
      for (int m = 0; m < 8; ++m)
        af[m] = *(const bf16x8*)(sb + aBase + m * 1024 + ck);
#pragma unroll
      for (int n = 0; n < 4; ++n)
        bv[n] = *(const bf16x8*)(sb + bBase + n * 1024 + ck);
      __builtin_amdgcn_s_setprio(1);
#pragma unroll
      for (int m = 0; m < 8; ++m)
#pragma unroll
        for (int n = 0; n < 4; ++n)
          acc[m][n] = __builtin_amdgcn_mfma_f32_16x16x32_bf16(af[m], bv[n], acc[m][n], 0, 0, 0);
      __builtin_amdgcn_s_setprio(0);
    }
  }

  // ---------- epilogue ----------
  if (EPI == 0) {
    u16* Hrow = Hout + (size_t)ez * MDIM * NDIM;
#pragma unroll
    for (int m = 0; m < 8; ++m) {
#pragma unroll
      for (int r = 0; r < 4; ++r) {
        int row = m0 + wr * 128 + m * 16 + (lane >> 4) * 4 + r;
#pragma unroll
        for (int n = 0; n < 4; ++n) {
          int col = n0 + wc * 64 + n * 16 + (lane & 15);
          Hrow[(size_t)row * NDIM + col] = f2bf(gelu_tanh(acc[m][n][r]));
        }
      }
    }
  } else {
#pragma unroll
    for (int m = 0; m < 8; ++m) {
#pragma unroll
      for (int r = 0; r < 4; ++r) {
        int slot_in_e = m0 + wr * 128 + m * 16 + (lane >> 4) * 4 + r;
        int gslot = e * CAP + slot_in_e;
        int s = tok_of_slot[gslot];
        if (s >= 0) {
          float g = gate_of_slot[gslot];
#pragma unroll
          for (int n = 0; n < 4; ++n) {
            int col = n0 + wc * 64 + n * 16 + (lane & 15);
            Fout[(size_t)s * NDIM + col] = g * acc[m][n][r];
          }
        }
      }
    }
  }
}

extern "C" void kernel_launch(void* const* d_in, const int* in_sizes, int n_in,
                              void* d_out, int out_size, void* d_ws, size_t ws_size,
                              hipStream_t stream) {
  (void)in_sizes; (void)n_in;
  const float* x  = (const float*)d_in[0];
  const float* wg = (const float*)d_in[1];
  const float* w1 = (const float*)d_in[2];
  const float* w2 = (const float*)d_in[3];
  float* out = (float*)d_out;

  char* ws = (char*)d_ws;
  size_t off = 0;
  auto alloc = [&](size_t b) {
    off = (off + 255) & ~(size_t)255;
    char* p = ws + off;
    off += b;
    return p;
  };
  int*   tok_expert   = (int*)alloc((size_t)S_TOK * 4);
  float* tok_gate     = (float*)alloc((size_t)S_TOK * 4);
  int*   tok_of_slot  = (int*)alloc((size_t)NE * CAP * 4);
  float* gate_of_slot = (float*)alloc((size_t)NE * CAP * 4);
  u16*   Xd           = (u16*)alloc((size_t)NE * CAP * DDIM * 2);
  size_t off_common = off;

  const size_t H_big  = (size_t)NE * CAP * FDIM * 2;   // 134 MB
  const size_t WT_big = (size_t)NE * DDIM * FDIM * 2;  // 268 MB
  const size_t H_sm   = (size_t)CAP * FDIM * 2;        // 16.8 MB
  const size_t WT_sm  = (size_t)DDIM * FDIM * 2;       // 33.5 MB
  bool big = ws_size >= off_common + H_big + WT_big + 1024;

  // fast zero of out (replaces slow rocclr fillBuffer); Xd zeroing is folded
  // into scatter_kernel (every slot row written each call).
  fill_zero_kernel<<<2048, 256, 0, stream>>>((float4*)out, out_size / 4);
  gating_kernel<<<S_TOK / 4, 256, 0, stream>>>(x, wg, tok_expert, tok_gate);
  init_slots<<<(NE * CAP) / 256, 256, 0, stream>>>(tok_of_slot, gate_of_slot);
  scan_kernel<<<1, 1024, 0, stream>>>(tok_expert, tok_gate, tok_of_slot, gate_of_slot);
  scatter_kernel<<<NE * CAP, 256, 0, stream>>>(tok_of_slot, x, Xd);

  if (big) {
    u16* H  = (u16*)alloc(H_big);
    u16* WT = (u16*)alloc(WT_big);
    convt_kernel<DDIM, FDIM><<<dim3(FDIM / 64, DDIM / 64, NE), 256, 0, stream>>>(w1, WT);
    moe_gemm<DDIM, FDIM, 0, NE><<<dim3(NE * 4 * (FDIM / 256)), 512, 0, stream>>>(
        Xd, WT, H, nullptr, tok_of_slot, gate_of_slot, 0);
    convt_kernel<FDIM, DDIM><<<dim3(DDIM / 64, FDIM / 64, NE), 256, 0, stream>>>(w2, WT);
    moe_gemm<FDIM, DDIM, 1, NE><<<dim3(NE * 4 * (DDIM / 256)), 512, 0, stream>>>(
        H, WT, nullptr, out, tok_of_slot, gate_of_slot, 0);
  } else {
    u16* H  = (u16*)alloc(H_sm);
    u16* WT = (u16*)alloc(WT_sm);
    for (int e = 0; e < NE; ++e) {
      convt_kernel<DDIM, FDIM><<<dim3(FDIM / 64, DDIM / 64, 1), 256, 0, stream>>>(
          w1 + (size_t)e * DDIM * FDIM, WT);
      moe_gemm<DDIM, FDIM, 0, 1><<<dim3(4 * (FDIM / 256)), 512, 0, stream>>>(
          Xd + (size_t)e * CAP * DDIM, WT, H, nullptr, tok_of_slot, gate_of_slot, e);
      convt_kernel<FDIM, DDIM><<<dim3(DDIM / 64, FDIM / 64, 1), 256, 0, stream>>>(
          w2 + (size_t)e * FDIM * DDIM, WT);
      moe_gemm<FDIM, DDIM, 1, 1><<<dim3(4 * (DDIM / 256)), 512, 0, stream>>>(
          H, WT, nullptr, out, tok_of_slot, gate_of_slot, e);
    }
  }
}

// Round 6
// 762.330 us; speedup vs baseline: 1.7566x; 1.1873x over previous
//
#include <hip/hip_runtime.h>

using u16 = unsigned short;
typedef __attribute__((ext_vector_type(4))) float f32x4;
typedef __attribute__((ext_vector_type(8))) short bf16x8;
typedef unsigned short u16x8 __attribute__((ext_vector_type(8)));

static constexpr int S_TOK = 8192;   // B*T
static constexpr int NE    = 8;      // experts
static constexpr int CAP   = 1024;   // capacity = S/E
static constexpr int DDIM  = 2048;   // model dim
static constexpr int FDIM  = 8192;   // ffn dim

#define S_WAIT_ALL() asm volatile("s_waitcnt vmcnt(0) lgkmcnt(0)" ::: "memory")
#define S_BAR()                                  \
  do {                                           \
    __builtin_amdgcn_sched_barrier(0);           \
    __builtin_amdgcn_s_barrier();                \
    __builtin_amdgcn_sched_barrier(0);           \
  } while (0)

__device__ __forceinline__ u16 f2bf(float f) {
  union { float fv; unsigned uv; } v; v.fv = f;
  unsigned r = v.uv + 0x7fffu + ((v.uv >> 16) & 1u);
  return (u16)(r >> 16);
}

__device__ __forceinline__ float gelu_tanh(float x) {
  float u = 0.7978845608028654f * (x + 0.044715f * x * x * x);
  float t = 1.0f - 2.0f / (__expf(2.0f * u) + 1.0f);
  return 0.5f * x * (1.0f + t);
}

__device__ __forceinline__ void gl_lds16(const void* g, void* l) {
  __builtin_amdgcn_global_load_lds(
      (const __attribute__((address_space(1))) unsigned int*)g,
      (__attribute__((address_space(3))) unsigned int*)l, 16, 0, 0);
}

// ---------------- fast zero fill ----------------
__global__ __launch_bounds__(256) void fill_zero_kernel(float4* __restrict__ p, int n4) {
  int i = blockIdx.x * 256 + threadIdx.x;
  int stride = gridDim.x * 256;
  float4 z = {0.f, 0.f, 0.f, 0.f};
  for (; i < n4; i += stride) p[i] = z;
}

// ---------------- gating: logits fp32, softmax, argmax ----------------
__global__ __launch_bounds__(256) void gating_kernel(
    const float* __restrict__ x, const float* __restrict__ wg,
    int* __restrict__ tok_expert, float* __restrict__ tok_gate) {
  int s = blockIdx.x * 4 + (threadIdx.x >> 6);
  int lane = threadIdx.x & 63;
  const float4* xv = (const float4*)(x + (size_t)s * DDIM + lane * 32);
  float acc[8];
#pragma unroll
  for (int e = 0; e < 8; ++e) acc[e] = 0.f;
#pragma unroll
  for (int j = 0; j < 8; ++j) {
    float4 xx = xv[j];
#pragma unroll
    for (int c = 0; c < 4; ++c) {
      int i = lane * 32 + j * 4 + c;
      const float4* wrow = (const float4*)(wg + (size_t)i * 8);
      float4 w0 = wrow[0], w1 = wrow[1];
      float xe = (c == 0) ? xx.x : (c == 1) ? xx.y : (c == 2) ? xx.z : xx.w;
      acc[0] += xe * w0.x; acc[1] += xe * w0.y; acc[2] += xe * w0.z; acc[3] += xe * w0.w;
      acc[4] += xe * w1.x; acc[5] += xe * w1.y; acc[6] += xe * w1.z; acc[7] += xe * w1.w;
    }
  }
#pragma unroll
  for (int off = 32; off > 0; off >>= 1)
#pragma unroll
    for (int e = 0; e < 8; ++e) acc[e] += __shfl_xor(acc[e], off, 64);
  if (lane == 0) {
    float m = acc[0]; int ai = 0;
#pragma unroll
    for (int e = 1; e < 8; ++e) if (acc[e] > m) { m = acc[e]; ai = e; }
    float sum = 0.f;
#pragma unroll
    for (int e = 0; e < 8; ++e) sum += expf(acc[e] - m);
    tok_expert[s] = ai;
    tok_gate[s] = 1.0f / sum;
  }
}

__global__ void init_slots(int* tok_of_slot, float* gate_of_slot) {
  int i = blockIdx.x * 256 + threadIdx.x;
  tok_of_slot[i] = -1;
  gate_of_slot[i] = 0.f;
}

// -------- deterministic capacity assignment (cumsum over token order) --------
__global__ __launch_bounds__(1024) void scan_kernel(
    const int* __restrict__ tok_expert, const float* __restrict__ tok_gate,
    int* __restrict__ tok_of_slot, float* __restrict__ gate_of_slot) {
  __shared__ int cnt[1024][8];
  int t = threadIdx.x;
  int e8[8];
  int local[8];
#pragma unroll
  for (int e = 0; e < 8; ++e) local[e] = 0;
#pragma unroll
  for (int j = 0; j < 8; ++j) {
    int e = tok_expert[t * 8 + j];
    e8[j] = e;
    local[e]++;
  }
#pragma unroll
  for (int e = 0; e < 8; ++e) cnt[t][e] = local[e];
  __syncthreads();
  for (int off = 1; off < 1024; off <<= 1) {
    int v[8];
    bool has = (t >= off);
    if (has) {
#pragma unroll
      for (int e = 0; e < 8; ++e) v[e] = cnt[t - off][e];
    }
    __syncthreads();
    if (has) {
#pragma unroll
      for (int e = 0; e < 8; ++e) cnt[t][e] += v[e];
    }
    __syncthreads();
  }
  int base[8];
#pragma unroll
  for (int e = 0; e < 8; ++e) base[e] = (t == 0) ? 0 : cnt[t - 1][e];
#pragma unroll
  for (int j = 0; j < 8; ++j) {
    int s = t * 8 + j;
    int e = e8[j];
    int p = base[e]++;
    if (p < CAP) {
      tok_of_slot[e * CAP + p] = s;
      gate_of_slot[e * CAP + p] = tok_gate[s];
    }
  }
}

// ---- dispatch: gather x rows -> bf16 Xd [E][CAP][D]; empty slots -> zeros ----
__global__ __launch_bounds__(256) void scatter_kernel(
    const int* __restrict__ tok_of_slot, const float* __restrict__ x,
    u16* __restrict__ Xd) {
  int slot = blockIdx.x;
  int s = tok_of_slot[slot];
  int t = threadIdx.x;
  u16x8 v;
  if (s >= 0) {
    const float4* xr = (const float4*)(x + (size_t)s * DDIM + t * 8);
    float4 a = xr[0], b = xr[1];
    v[0] = f2bf(a.x); v[1] = f2bf(a.y); v[2] = f2bf(a.z); v[3] = f2bf(a.w);
    v[4] = f2bf(b.x); v[5] = f2bf(b.y); v[6] = f2bf(b.z); v[7] = f2bf(b.w);
  } else {
#pragma unroll
    for (int j = 0; j < 8; ++j) v[j] = 0;
  }
  *(u16x8*)(Xd + (size_t)slot * DDIM + t * 8) = v;
}

// ---- pipelined bf16 GEMM with fused fp32->bf16 weight staging ----
// C[1024xN] = A[1024xK](bf16) * W[KxN](fp32, row-major).
// BM=BN=256, BK=64, 512 thr / 8 waves (2M x 4N), wave-tile 128x64.
// A: global_load_lds w=16, pre-swizzled source. B: reg-staged — per K-tile each
// thread 8x global_load_dwordx4 (1 k-row, 4 n), cvt to bf16, 4x ds_write_b128
// into the XOR-swizzled [n][k] tile (write/read same involution).
// One vmcnt(0)+lgkmcnt(0)+barrier per K-tile; prefetch issued right after the
// barrier, MFMA body covers the latency, cvt+write land at body end.
// EPI=0: gelu -> bf16 H ; EPI=1: gated scatter to fp32 out.
template <int KDIM, int NDIM, int EPI, int NEXP>
__global__ __launch_bounds__(512, 2) void moe_gemm(
    const u16* __restrict__ A, const float* __restrict__ Bf,
    u16* __restrict__ Hout, float* __restrict__ Fout,
    const int* __restrict__ tok_of_slot, const float* __restrict__ gate_of_slot,
    int e_base) {
  constexpr int MDIM = 1024;
  constexpr int BM = 256, BN = 256, BK = 64;
  constexpr int MT = MDIM / BM;              // 4
  constexpr int NK = KDIM / BK;
  constexpr int ASZ = BM * BK;               // 16384 u16 (32 KB)
  constexpr int BSZ = BN * BK;               // 16384 u16 (32 KB)
  constexpr int BUFSZ = ASZ + BSZ;
  __shared__ u16 lds[2 * BUFSZ];             // 128 KB

  const int t = threadIdx.x;
  const int lane = t & 63, wave = t >> 6;
  const int wr = wave >> 2, wc = wave & 3;   // 2 x 4

  int id = blockIdx.x;
  int ez = id & (NEXP - 1);
  int w = id / NEXP;
  int mt = w & (MT - 1);
  int nt = w / MT;
  int m0 = mt * BM, n0 = nt * BN;
  int e = e_base + ez;

  const u16* Ae = A + (size_t)ez * MDIM * KDIM;
  const float* Be = Bf + (size_t)ez * (size_t)KDIM * NDIM;

  // A staging (global_load_lds, pre-swizzled source)
  const u16* aSrc[4];
  int ldsOffA[4];
#pragma unroll
  for (int p = 0; p < 4; ++p) {
    int c = t + p * 512;
    int row = c >> 3;
    int j = (c & 7) ^ (row & 7);
    aSrc[p] = Ae + (size_t)(m0 + row) * KDIM + j * 8;
    ldsOffA[p] = c * 8;
  }

  // B reg staging: thread -> (n-quad, k-oct)
  const int bq = (t & 63) * 4;     // n base (0..252), lanes contiguous in n
  const int boct = t >> 6;         // k-oct 0..7 (= wave id)
  const float* bP = Be + (size_t)(boct * 8) * NDIM + n0 + bq;
  // ds_write targets: rows bq+c, physical 16B slot = boct ^ (row&7)
  int bWOff[4];
#pragma unroll
  for (int c = 0; c < 4; ++c) {
    int row = bq + c;
    bWOff[c] = ASZ + row * 64 + (boct ^ (row & 7)) * 8;  // u16 units
  }

  // ds_read addressing (u16 offsets within buffer)
  const int aBase = (wr * 128 + (lane & 15)) * 64;        // A row base
  const int bBase = ASZ + (wc * 64 + (lane & 15)) * 64;   // B row base
  const int swz = (lane & 7) << 4;                        // byte key
  const int cK0 = ((((lane >> 4) * 16)) ^ swz) >> 1;      // kk=0, u16
  const int cK1 = ((64 + (lane >> 4) * 16) ^ swz) >> 1;   // kk=1, u16

  f32x4 acc[8][4];
#pragma unroll
  for (int m = 0; m < 8; ++m)
#pragma unroll
    for (int n = 0; n < 4; ++n) acc[m][n] = f32x4{0.f, 0.f, 0.f, 0.f};

  f32x4 bv4[8];

  // ---- prologue: stage K-tile 0 into buffer 0 ----
#pragma unroll
  for (int p = 0; p < 4; ++p) gl_lds16(aSrc[p], &lds[ldsOffA[p]]);
#pragma unroll
  for (int j = 0; j < 8; ++j) bv4[j] = *(const f32x4*)(bP + (size_t)j * NDIM);
#pragma unroll
  for (int c = 0; c < 4; ++c) {
    u16x8 o;
#pragma unroll
    for (int j = 0; j < 8; ++j) o[j] = f2bf(bv4[j][c]);
    *(u16x8*)(&lds[bWOff[c]]) = o;
  }
  S_WAIT_ALL();
  S_BAR();

  for (int kt = 0; kt < NK; ++kt) {
    const u16* sb = &lds[(kt & 1) * BUFSZ];
    u16* nb = &lds[((kt + 1) & 1) * BUFSZ];
    const bool pre = (kt + 1 < NK);
    if (pre) {
      const int ko = (kt + 1) * BK;
#pragma unroll
      for (int p = 0; p < 4; ++p) gl_lds16(aSrc[p] + ko, nb + ldsOffA[p]);
#pragma unroll
      for (int j = 0; j < 8; ++j)
        bv4[j] = *(const f32x4*)(bP + (size_t)(ko + j) * NDIM);
    }

#pragma unroll
    for (int kk = 0; kk < 2; ++kk) {
      const int ck = kk ? cK1 : cK0;
      bf16x8 af[8], bv[4];
#pragma unroll
      for (int m = 0; m < 8; ++m)
        af[m] = *(const bf16x8*)(sb + aBase + m * 1024 + ck);
#pragma unroll
      for (int n = 0; n < 4; ++n)
        bv[n] = *(const bf16x8*)(sb + bBase + n * 1024 + ck);
      __builtin_amdgcn_s_setprio(1);
#pragma unroll
      for (int m = 0; m < 8; ++m)
#pragma unroll
        for (int n = 0; n < 4; ++n)
          acc[m][n] = __builtin_amdgcn_mfma_f32_16x16x32_bf16(af[m], bv[n], acc[m][n], 0, 0, 0);
      __builtin_amdgcn_s_setprio(0);
    }

    if (pre) {
#pragma unroll
      for (int c = 0; c < 4; ++c) {
        u16x8 o;
#pragma unroll
        for (int j = 0; j < 8; ++j) o[j] = f2bf(bv4[j][c]);
        *(u16x8*)(nb + bWOff[c]) = o;
      }
    }
    S_WAIT_ALL();
    S_BAR();
  }

  // ---------- epilogue ----------
  if (EPI == 0) {
    u16* Hrow = Hout + (size_t)ez * MDIM * NDIM;
#pragma unroll
    for (int m = 0; m < 8; ++m) {
#pragma unroll
      for (int r = 0; r < 4; ++r) {
        int row = m0 + wr * 128 + m * 16 + (lane >> 4) * 4 + r;
#pragma unroll
        for (int n = 0; n < 4; ++n) {
          int col = n0 + wc * 64 + n * 16 + (lane & 15);
          Hrow[(size_t)row * NDIM + col] = f2bf(gelu_tanh(acc[m][n][r]));
        }
      }
    }
  } else {
#pragma unroll
    for (int m = 0; m < 8; ++m) {
#pragma unroll
      for (int r = 0; r < 4; ++r) {
        int slot_in_e = m0 + wr * 128 + m * 16 + (lane >> 4) * 4 + r;
        int gslot = e * CAP + slot_in_e;
        int s = tok_of_slot[gslot];
        if (s >= 0) {
          float g = gate_of_slot[gslot];
#pragma unroll
          for (int n = 0; n < 4; ++n) {
            int col = n0 + wc * 64 + n * 16 + (lane & 15);
            Fout[(size_t)s * NDIM + col] = g * acc[m][n][r];
          }
        }
      }
    }
  }
}

extern "C" void kernel_launch(void* const* d_in, const int* in_sizes, int n_in,
                              void* d_out, int out_size, void* d_ws, size_t ws_size,
                              hipStream_t stream) {
  (void)in_sizes; (void)n_in;
  const float* x  = (const float*)d_in[0];
  const float* wg = (const float*)d_in[1];
  const float* w1 = (const float*)d_in[2];
  const float* w2 = (const float*)d_in[3];
  float* out = (float*)d_out;

  char* ws = (char*)d_ws;
  size_t off = 0;
  auto alloc = [&](size_t b) {
    off = (off + 255) & ~(size_t)255;
    char* p = ws + off;
    off += b;
    return p;
  };
  int*   tok_expert   = (int*)alloc((size_t)S_TOK * 4);
  float* tok_gate     = (float*)alloc((size_t)S_TOK * 4);
  int*   tok_of_slot  = (int*)alloc((size_t)NE * CAP * 4);
  float* gate_of_slot = (float*)alloc((size_t)NE * CAP * 4);
  u16*   Xd           = (u16*)alloc((size_t)NE * CAP * DDIM * 2);
  size_t off_common = off;

  const size_t H_big = (size_t)NE * CAP * FDIM * 2;   // 134 MB
  const size_t H_sm  = (size_t)CAP * FDIM * 2;        // 16.8 MB
  bool big = ws_size >= off_common + H_big + 1024;

  fill_zero_kernel<<<2048, 256, 0, stream>>>((float4*)out, out_size / 4);
  gating_kernel<<<S_TOK / 4, 256, 0, stream>>>(x, wg, tok_expert, tok_gate);
  init_slots<<<(NE * CAP) / 256, 256, 0, stream>>>(tok_of_slot, gate_of_slot);
  scan_kernel<<<1, 1024, 0, stream>>>(tok_expert, tok_gate, tok_of_slot, gate_of_slot);
  scatter_kernel<<<NE * CAP, 256, 0, stream>>>(tok_of_slot, x, Xd);

  if (big) {
    u16* H = (u16*)alloc(H_big);
    moe_gemm<DDIM, FDIM, 0, NE><<<dim3(NE * 4 * (FDIM / 256)), 512, 0, stream>>>(
        Xd, w1, H, nullptr, tok_of_slot, gate_of_slot, 0);
    moe_gemm<FDIM, DDIM, 1, NE><<<dim3(NE * 4 * (DDIM / 256)), 512, 0, stream>>>(
        H, w2, nullptr, out, tok_of_slot, gate_of_slot, 0);
  } else {
    u16* H = (u16*)alloc(H_sm);
    for (int e = 0; e < NE; ++e) {
      moe_gemm<DDIM, FDIM, 0, 1><<<dim3(4 * (FDIM / 256)), 512, 0, stream>>>(
          Xd + (size_t)e * CAP * DDIM, w1 + (size_t)e * DDIM * FDIM, H, nullptr,
          tok_of_slot, gate_of_slot, e);
      moe_gemm<FDIM, DDIM, 1, 1><<<dim3(4 * (DDIM / 256)), 512, 0, stream>>>(
          H, w2 + (size_t)e * FDIM * DDIM, nullptr, out,
          tok_of_slot, gate_of_slot, e);
    }
  }
}